// Round 4
// baseline (893.497 us; speedup 1.0000x reference)
//
#include <hip/hip_runtime.h>
#include <cstdint>
#include <cstddef>

#define NFEAT 500
#define NHID  128
#define NCLASS 40

typedef __attribute__((ext_vector_type(8))) short bf16x8;
typedef __attribute__((ext_vector_type(4))) float f32x4;

__device__ __forceinline__ unsigned short f2bf(float f) {
    union { float f; unsigned u; } v; v.f = f;
    unsigned u = v.u;
    unsigned r = u + 0x7FFF + ((u >> 16) & 1);   // round-to-nearest-even
    return (unsigned short)(r >> 16);
}
__device__ __forceinline__ float bf2f(unsigned short h) {
    union { unsigned u; float f; } v; v.u = ((unsigned)h) << 16; return v.f;
}

__device__ __forceinline__ bf16x8 cvt8(float4 a, float4 b) {
    union { bf16x8 v; unsigned u[4]; } r;
    r.u[0] = (unsigned)f2bf(a.x) | ((unsigned)f2bf(a.y) << 16);
    r.u[1] = (unsigned)f2bf(a.z) | ((unsigned)f2bf(a.w) << 16);
    r.u[2] = (unsigned)f2bf(b.x) | ((unsigned)f2bf(b.y) << 16);
    r.u[3] = (unsigned)f2bf(b.z) | ((unsigned)f2bf(b.w) << 16);
    return r.v;
}

// ---------------- CSR construction ----------------

__global__ void k_hist(const int* __restrict__ row, int E, int* __restrict__ counts) {
    int i = blockIdx.x * 256 + threadIdx.x;
    if (i < E) atomicAdd(&counts[row[i]], 1);
}

__global__ void k_block_sum(const int* __restrict__ counts, int n, int* __restrict__ partials) {
    __shared__ int tmp[256];
    int i = blockIdx.x * 256 + threadIdx.x;
    tmp[threadIdx.x] = (i < n) ? counts[i] : 0;
    __syncthreads();
    for (int o = 128; o > 0; o >>= 1) {
        if (threadIdx.x < o) tmp[threadIdx.x] += tmp[threadIdx.x + o];
        __syncthreads();
    }
    if (threadIdx.x == 0) partials[blockIdx.x] = tmp[0];
}

__global__ void k_scan_partials(int* __restrict__ partials, int nb) {
    __shared__ int tmp[512];
    int t = threadIdx.x;
    int v = (t < nb) ? partials[t] : 0;
    tmp[t] = v;
    __syncthreads();
    for (int o = 1; o < 512; o <<= 1) {
        int add = (t >= o) ? tmp[t - o] : 0;
        __syncthreads();
        tmp[t] += add;
        __syncthreads();
    }
    if (t < nb) partials[t] = tmp[t] - v;   // exclusive
}

// also zeroes counts for reuse as cursor
__global__ void k_scan_counts(int* __restrict__ counts, const int* __restrict__ partials,
                              int* __restrict__ row_ptr, int n) {
    __shared__ int tmp[256];
    int t = threadIdx.x;
    int i = blockIdx.x * 256 + t;
    int v = (i < n) ? counts[i] : 0;
    tmp[t] = v;
    __syncthreads();
    for (int o = 1; o < 256; o <<= 1) {
        int add = (t >= o) ? tmp[t - o] : 0;
        __syncthreads();
        tmp[t] += add;
        __syncthreads();
    }
    int incl = tmp[t];
    int base = partials[blockIdx.x];
    if (i < n) {
        row_ptr[i] = base + incl - v;
        counts[i] = 0;
    }
    if (i == n - 1) row_ptr[n] = base + incl;
}

__global__ void k_scatter(const int* __restrict__ row, const int* __restrict__ col,
                          const float* __restrict__ w, int E,
                          const int* __restrict__ row_ptr, int* __restrict__ cursor,
                          uint2* __restrict__ csr_cw) {
    int i = blockIdx.x * 256 + threadIdx.x;
    if (i < E) {
        int r = row[i];
        int p = row_ptr[r] + atomicAdd(&cursor[r], 1);
        csr_cw[p] = make_uint2((unsigned)col[i], __float_as_uint(w[i]));
    }
}

// ---------------- weight prep: W[K][N] fp32 -> Wt[Nt][Kpad] bf16 (transposed, zero-padded) ----------------

__global__ void k_prep_w(const float* __restrict__ W, unsigned short* __restrict__ Wt,
                         int K, int Norig, int Nt, int Kpad) {
    int idx = blockIdx.x * 256 + threadIdx.x;
    if (idx >= Nt * Kpad) return;
    int n = idx / Kpad, k = idx % Kpad;
    unsigned short v = 0;
    if (k < K && n < Norig) v = f2bf(W[(size_t)k * Norig + n]);
    Wt[idx] = v;
}

// ---------------- Layer-1 GEMM: fp32 A[M][500] @ Wt1^T -> bf16 C[Mpad][128] ----------------
// Direct (no LDS, no barriers; round 3 proved A has zero cross-wave reuse).
// Round-3 diagnosis: grid-limited occupancy (~1.75 waves/SIMD) + loads issued
// immediately before consuming MFMAs -> ~60-70% vmcnt stall per iter. Fix = ILP:
// rotate-3 register staging, A-loads issued 2 iterations ahead of use; K=500
// hardcoded so the 15-iteration pipeline fully unrolls and guards fold away.
// B fragments stay just-in-time (Wt1 128KB = L2-hot; co-resident waves cover it).

#define LDA1(V0, V1, V2, V3, IT)                                   \
    do {                                                           \
        const float* p0_ = ap0 + (IT) * 32;                        \
        const float* p1_ = ap1 + (IT) * 32;                        \
        V0 = *(const float4*)p0_;  V1 = *(const float4*)(p0_ + 4); \
        V2 = *(const float4*)p1_;  V3 = *(const float4*)(p1_ + 4); \
    } while (0)

#define CMP1(V0, V1, V2, V3, IT)                                                             \
    do {                                                                                     \
        bf16x8 bfr_[8];                                                                      \
        _Pragma("unroll")                                                                    \
        for (int ni_ = 0; ni_ < 8; ni_++)                                                    \
            bfr_[ni_] = *(const bf16x8*)(bp + (size_t)(ni_ * 16) * 512 + (IT) * 32);         \
        bf16x8 af0_ = cvt8(V0, V1);                                                          \
        bf16x8 af1_ = cvt8(V2, V3);                                                          \
        _Pragma("unroll")                                                                    \
        for (int ni_ = 0; ni_ < 8; ni_++) {                                                  \
            acc[0][ni_] = __builtin_amdgcn_mfma_f32_16x16x32_bf16(af0_, bfr_[ni_], acc[0][ni_], 0, 0, 0); \
            acc[1][ni_] = __builtin_amdgcn_mfma_f32_16x16x32_bf16(af1_, bfr_[ni_], acc[1][ni_], 0, 0, 0); \
        }                                                                                    \
    } while (0)

__global__ __launch_bounds__(256) void k_gemm_l1(const float* __restrict__ A,
                                                 const unsigned short* __restrict__ Wt,
                                                 unsigned short* __restrict__ C, int M) {
    constexpr int K = 500;
    const int t = threadIdx.x;
    const int lane = t & 63;
    const int l15 = lane & 15, quad = lane >> 4;
    const int wave = blockIdx.x * 4 + (t >> 6);
    const int m0 = wave * 32;

    // clamp OOB rows to a valid row: garbage lands only in padded C rows (never read)
    const int r0 = m0 + l15, r1 = r0 + 16;
    const int rc0 = (r0 < M) ? r0 : M - 1;
    const int rc1 = (r1 < M) ? r1 : M - 1;
    const float* ap0 = A + (size_t)rc0 * K + quad * 8;
    const float* ap1 = A + (size_t)rc1 * K + quad * 8;
    const unsigned short* bp = Wt + (size_t)l15 * 512 + quad * 8;

    f32x4 acc[2][8];
#pragma unroll
    for (int mi = 0; mi < 2; mi++)
#pragma unroll
        for (int ni = 0; ni < 8; ni++)
            acc[mi][ni] = (f32x4){0.f, 0.f, 0.f, 0.f};

    // rotate-3 staging sets (named float4s -> SROA-trivial)
    float4 sa0, sa1, sa2, sa3;   // set A
    float4 sb0, sb1, sb2, sb3;   // set B
    float4 sc0, sc1, sc2, sc3;   // set C

    LDA1(sa0, sa1, sa2, sa3, 0);
    LDA1(sb0, sb1, sb2, sb3, 1);
#pragma unroll
    for (int it = 0; it < 15; it += 3) {
        LDA1(sc0, sc1, sc2, sc3, it + 2);            // depth-2 prefetch
        CMP1(sa0, sa1, sa2, sa3, it);
        if (it + 3 < 15) LDA1(sa0, sa1, sa2, sa3, it + 3);
        CMP1(sb0, sb1, sb2, sb3, it + 1);
        if (it + 4 < 15) LDA1(sb0, sb1, sb2, sb3, it + 4);
        CMP1(sc0, sc1, sc2, sc3, it + 2);
    }

    // K tail: k = 480..499 (Wt zero-padded to 512, so only memory-guard A reads)
    {
        float va[8], vb[8];
#pragma unroll
        for (int j = 0; j < 8; j++) {
            int gk = 480 + quad * 8 + j;
            va[j] = (gk < K) ? ap0[15 * 32 + j] : 0.f;
            vb[j] = (gk < K) ? ap1[15 * 32 + j] : 0.f;
        }
        float4 t0 = make_float4(va[0], va[1], va[2], va[3]);
        float4 t1 = make_float4(va[4], va[5], va[6], va[7]);
        float4 t2 = make_float4(vb[0], vb[1], vb[2], vb[3]);
        float4 t3 = make_float4(vb[4], vb[5], vb[6], vb[7]);
        CMP1(t0, t1, t2, t3, 15);
    }

    // epilogue: C/D layout col=lane&15, row=quad*4+reg ; C rows padded, no guards
#pragma unroll
    for (int mi = 0; mi < 2; mi++) {
#pragma unroll
        for (int r = 0; r < 4; r++) {
            int gm = m0 + mi * 16 + quad * 4 + r;
#pragma unroll
            for (int ni = 0; ni < 8; ni++)
                C[(size_t)gm * 128 + ni * 16 + l15] = f2bf(acc[mi][ni][r]);
        }
    }
}

// ---------------- bf16 GEMM (Kpad=128, 4 K-iters): A bf16 [Mpad][128] @ Wt^T ----------------
// All 4 iterations' A fragments issued up-front (8 loads in flight), then
// 4 x (B-frag JIT load + MFMA). No LDS, no barriers, no M guards (padded buffers).

template<int TN, int CN, int CPITCH>
__global__ __launch_bounds__(256) void k_gemm_b(const unsigned short* __restrict__ A,
                                                const unsigned short* __restrict__ Wt,
                                                unsigned short* __restrict__ C) {
    const int t = threadIdx.x;
    const int lane = t & 63;
    const int l15 = lane & 15, quad = lane >> 4;
    const int wave = blockIdx.x * 4 + (t >> 6);
    const int m0 = wave * 32;
    const int r0 = m0 + l15, r1 = r0 + 16;

    const unsigned short* ap0 = A + (size_t)r0 * 128 + quad * 8;
    const unsigned short* ap1 = A + (size_t)r1 * 128 + quad * 8;
    const unsigned short* bp = Wt + (size_t)l15 * 128 + quad * 8;

    f32x4 acc[2][TN];
#pragma unroll
    for (int mi = 0; mi < 2; mi++)
#pragma unroll
        for (int ni = 0; ni < TN; ni++)
            acc[mi][ni] = (f32x4){0.f, 0.f, 0.f, 0.f};

    // all A fragments up-front: 8 x 16B loads in flight
    bf16x8 a00 = *(const bf16x8*)(ap0);       bf16x8 a01 = *(const bf16x8*)(ap1);
    bf16x8 a10 = *(const bf16x8*)(ap0 + 32);  bf16x8 a11 = *(const bf16x8*)(ap1 + 32);
    bf16x8 a20 = *(const bf16x8*)(ap0 + 64);  bf16x8 a21 = *(const bf16x8*)(ap1 + 64);
    bf16x8 a30 = *(const bf16x8*)(ap0 + 96);  bf16x8 a31 = *(const bf16x8*)(ap1 + 96);

#define CMPB(AF0, AF1, IT)                                                                   \
    do {                                                                                     \
        bf16x8 bfr_[TN];                                                                     \
        _Pragma("unroll")                                                                    \
        for (int ni_ = 0; ni_ < TN; ni_++)                                                   \
            bfr_[ni_] = *(const bf16x8*)(bp + (size_t)(ni_ * 16) * 128 + (IT) * 32);         \
        _Pragma("unroll")                                                                    \
        for (int ni_ = 0; ni_ < TN; ni_++) {                                                 \
            acc[0][ni_] = __builtin_amdgcn_mfma_f32_16x16x32_bf16(AF0, bfr_[ni_], acc[0][ni_], 0, 0, 0); \
            acc[1][ni_] = __builtin_amdgcn_mfma_f32_16x16x32_bf16(AF1, bfr_[ni_], acc[1][ni_], 0, 0, 0); \
        }                                                                                    \
    } while (0)

    CMPB(a00, a01, 0);
    CMPB(a10, a11, 1);
    CMPB(a20, a21, 2);
    CMPB(a30, a31, 3);
#undef CMPB

#pragma unroll
    for (int mi = 0; mi < 2; mi++) {
#pragma unroll
        for (int r = 0; r < 4; r++) {
            int gm = m0 + mi * 16 + quad * 4 + r;
#pragma unroll
            for (int ni = 0; ni < TN; ni++) {
                int gn = ni * 16 + l15;
                if (gn < CN) C[(size_t)gm * CPITCH + gn] = f2bf(acc[mi][ni][r]);
            }
        }
    }
}

// ---------------- SpMM (width 128, bf16) + bias + optional ReLU ----------------

__global__ __launch_bounds__(256) void k_spmm128(const unsigned short* __restrict__ S,
                                                 const int* __restrict__ rp,
                                                 const uint2* __restrict__ cw,
                                                 const float* __restrict__ bias,
                                                 unsigned short* __restrict__ out,
                                                 int n, int do_relu) {
    int wid  = threadIdx.x >> 6;
    int lane = threadIdx.x & 63;
    int node = blockIdx.x * 4 + wid;
    if (node >= n) return;
    int s = rp[node], e = rp[node + 1];
    float a0x = 0.f, a0y = 0.f, a1x = 0.f, a1y = 0.f;
    float a2x = 0.f, a2y = 0.f, a3x = 0.f, a3y = 0.f;
    int i = s;
    for (; i + 4 <= e; i += 4) {
        uint2 e0 = cw[i], e1 = cw[i + 1], e2 = cw[i + 2], e3 = cw[i + 3];
        unsigned v0 = ((const unsigned*)(S + (size_t)e0.x * NHID))[lane];
        unsigned v1 = ((const unsigned*)(S + (size_t)e1.x * NHID))[lane];
        unsigned v2 = ((const unsigned*)(S + (size_t)e2.x * NHID))[lane];
        unsigned v3 = ((const unsigned*)(S + (size_t)e3.x * NHID))[lane];
        float w0 = __uint_as_float(e0.y), w1 = __uint_as_float(e1.y);
        float w2 = __uint_as_float(e2.y), w3 = __uint_as_float(e3.y);
        a0x = fmaf(w0, bf2f((unsigned short)v0), a0x); a0y = fmaf(w0, bf2f((unsigned short)(v0 >> 16)), a0y);
        a1x = fmaf(w1, bf2f((unsigned short)v1), a1x); a1y = fmaf(w1, bf2f((unsigned short)(v1 >> 16)), a1y);
        a2x = fmaf(w2, bf2f((unsigned short)v2), a2x); a2y = fmaf(w2, bf2f((unsigned short)(v2 >> 16)), a2y);
        a3x = fmaf(w3, bf2f((unsigned short)v3), a3x); a3y = fmaf(w3, bf2f((unsigned short)(v3 >> 16)), a3y);
    }
    for (; i < e; i++) {
        uint2 e0 = cw[i];
        unsigned v0 = ((const unsigned*)(S + (size_t)e0.x * NHID))[lane];
        float w0 = __uint_as_float(e0.y);
        a0x = fmaf(w0, bf2f((unsigned short)v0), a0x); a0y = fmaf(w0, bf2f((unsigned short)(v0 >> 16)), a0y);
    }
    float ax = (a0x + a1x) + (a2x + a3x) + bias[lane * 2];
    float ay = (a0y + a1y) + (a2y + a3y) + bias[lane * 2 + 1];
    if (do_relu) {
        ax = fmaxf(ax, 0.f);
        ay = fmaxf(ay, 0.f);
    }
    unsigned o = (unsigned)f2bf(ax) | ((unsigned)f2bf(ay) << 16);
    __builtin_nontemporal_store(o, (unsigned*)(out + (size_t)node * NHID) + lane);
}

// ---------------- SpMM (width 40, bf16 pitch 40) + bias + log_softmax -> fp32 out ----------------

__global__ __launch_bounds__(256) void k_spmm40_lsm(const unsigned short* __restrict__ S,
                                                    const int* __restrict__ rp,
                                                    const uint2* __restrict__ cw,
                                                    const float* __restrict__ bias,
                                                    float* __restrict__ out,
                                                    int n) {
    int wid  = threadIdx.x >> 6;
    int lane = threadIdx.x & 63;
    int node = blockIdx.x * 4 + wid;
    if (node >= n) return;
    int s = rp[node], e = rp[node + 1];
    float a0 = 0.f, a1 = 0.f, a2 = 0.f, a3 = 0.f;
    int i = s;
    bool act = lane < NCLASS;
    for (; i + 4 <= e; i += 4) {
        uint2 e0 = cw[i], e1 = cw[i + 1], e2 = cw[i + 2], e3 = cw[i + 3];
        if (act) {
            float v0 = bf2f(S[(size_t)e0.x * NCLASS + lane]);
            float v1 = bf2f(S[(size_t)e1.x * NCLASS + lane]);
            float v2 = bf2f(S[(size_t)e2.x * NCLASS + lane]);
            float v3 = bf2f(S[(size_t)e3.x * NCLASS + lane]);
            a0 = fmaf(__uint_as_float(e0.y), v0, a0);
            a1 = fmaf(__uint_as_float(e1.y), v1, a1);
            a2 = fmaf(__uint_as_float(e2.y), v2, a2);
            a3 = fmaf(__uint_as_float(e3.y), v3, a3);
        }
    }
    for (; i < e; i++) {
        uint2 e0 = cw[i];
        if (act) a0 = fmaf(__uint_as_float(e0.y), bf2f(S[(size_t)e0.x * NCLASS + lane]), a0);
    }
    float acc = (a0 + a1) + (a2 + a3);
    float logit = act ? acc + bias[lane] : -INFINITY;
    float m = logit;
#pragma unroll
    for (int o = 32; o >= 1; o >>= 1) m = fmaxf(m, __shfl_xor(m, o, 64));
    float ex = act ? expf(logit - m) : 0.f;
    float ssum = ex;
#pragma unroll
    for (int o = 32; o >= 1; o >>= 1) ssum += __shfl_xor(ssum, o, 64);
    if (act) {
        float r = logit - m - logf(ssum);
        __builtin_nontemporal_store(r, out + (size_t)node * NCLASS + lane);
    }
}

// ---------------- launch ----------------

extern "C" void kernel_launch(void* const* d_in, const int* in_sizes, int n_in,
                              void* d_out, int out_size, void* d_ws, size_t ws_size,
                              hipStream_t stream) {
    const float* x  = (const float*)d_in[0];
    const int* row  = (const int*)d_in[1];
    const int* col  = (const int*)d_in[2];
    const float* ew = (const float*)d_in[3];
    const float* W1 = (const float*)d_in[4];
    const float* b1 = (const float*)d_in[5];
    const float* W2 = (const float*)d_in[6];
    const float* b2 = (const float*)d_in[7];
    const float* W3 = (const float*)d_in[8];
    const float* b3 = (const float*)d_in[9];
    const float* W4 = (const float*)d_in[10];
    const float* b4 = (const float*)d_in[11];
    float* out = (float*)d_out;

    const int Nn = in_sizes[0] / NFEAT;
    const int E  = in_sizes[1];
    const int NB = (Nn + 255) / 256;
    const int Mpad = (Nn + 127) & ~127;

    char* ws = (char*)d_ws;
    size_t off = 0;
    auto alloc = [&](size_t bytes) {
        size_t o = off;
        off = (off + bytes + 255) & ~(size_t)255;
        return o;
    };
    int*   row_ptr  = (int*)(ws + alloc((size_t)(Nn + 1) * 4));
    int*   counts   = (int*)(ws + alloc((size_t)Nn * 4));       // also reused as cursor
    int*   partials = (int*)(ws + alloc((size_t)NB * 4));
    uint2* csr_cw   = (uint2*)(ws + alloc((size_t)E * 8));
    unsigned short* Sb  = (unsigned short*)(ws + alloc((size_t)Mpad * NHID * 2));
    unsigned short* Hb  = (unsigned short*)(ws + alloc((size_t)Mpad * NHID * 2));
    unsigned short* S4b = (unsigned short*)(ws + alloc((size_t)Mpad * NCLASS * 2));
    unsigned short* Wt1 = (unsigned short*)(ws + alloc((size_t)128 * 512 * 2));
    unsigned short* Wt2 = (unsigned short*)(ws + alloc((size_t)128 * 128 * 2));
    unsigned short* Wt3 = (unsigned short*)(ws + alloc((size_t)128 * 128 * 2));
    unsigned short* Wt4 = (unsigned short*)(ws + alloc((size_t)48 * 128 * 2));

    // ---- weight prep ----
    k_prep_w<<<(128 * 512 + 255) / 256, 256, 0, stream>>>(W1, Wt1, NFEAT, NHID, 128, 512);
    k_prep_w<<<(128 * 128 + 255) / 256, 256, 0, stream>>>(W2, Wt2, NHID, NHID, 128, 128);
    k_prep_w<<<(128 * 128 + 255) / 256, 256, 0, stream>>>(W3, Wt3, NHID, NHID, 128, 128);
    k_prep_w<<<(48 * 128 + 255) / 256, 256, 0, stream>>>(W4, Wt4, NHID, NCLASS, 48, 128);

    // ---- CSR build ----
    (void)hipMemsetAsync(counts, 0, (size_t)Nn * 4, stream);
    k_hist<<<(E + 255) / 256, 256, 0, stream>>>(row, E, counts);
    k_block_sum<<<NB, 256, 0, stream>>>(counts, Nn, partials);
    k_scan_partials<<<1, 512, 0, stream>>>(partials, NB);
    k_scan_counts<<<NB, 256, 0, stream>>>(counts, partials, row_ptr, Nn);
    k_scatter<<<(E + 255) / 256, 256, 0, stream>>>(row, col, ew, E, row_ptr, counts, csr_cw);

    const int gblocks = Mpad / 128;             // 4 waves/block x 32 rows/wave
    const int spmm_blocks = (Nn + 3) / 4;

    // layer 1: x @ W1 -> Sb ; spmm+b1+relu -> Hb
    k_gemm_l1<<<gblocks, 256, 0, stream>>>(x, Wt1, Sb, Nn);
    k_spmm128<<<spmm_blocks, 256, 0, stream>>>(Sb, row_ptr, csr_cw, b1, Hb, Nn, 1);
    // layer 2
    k_gemm_b<8, 128, 128><<<gblocks, 256, 0, stream>>>(Hb, Wt2, Sb);
    k_spmm128<<<spmm_blocks, 256, 0, stream>>>(Sb, row_ptr, csr_cw, b2, Hb, Nn, 1);
    // layer 3
    k_gemm_b<8, 128, 128><<<gblocks, 256, 0, stream>>>(Hb, Wt3, Sb);
    k_spmm128<<<spmm_blocks, 256, 0, stream>>>(Sb, row_ptr, csr_cw, b3, Hb, Nn, 1);
    // layer 4: Hb @ W4 -> S4b[N,40] ; spmm+b4+log_softmax -> out (fp32)
    k_gemm_b<3, 40, 40><<<gblocks, 256, 0, stream>>>(Hb, Wt4, S4b);
    k_spmm40_lsm<<<spmm_blocks, 256, 0, stream>>>(S4b, row_ptr, csr_cw, b4, out, Nn);
}

// Round 5
// 885.035 us; speedup vs baseline: 1.0096x; 1.0096x over previous
//
#include <hip/hip_runtime.h>
#include <cstdint>
#include <cstddef>

#define NFEAT 500
#define NHID  128
#define NCLASS 40

typedef __attribute__((ext_vector_type(8))) short bf16x8;
typedef __attribute__((ext_vector_type(4))) float f32x4;
typedef const __attribute__((address_space(1))) void* gas_t;
typedef __attribute__((address_space(3))) void* las_t;

__device__ __forceinline__ unsigned short f2bf(float f) {
    union { float f; unsigned u; } v; v.f = f;
    unsigned u = v.u;
    unsigned r = u + 0x7FFF + ((u >> 16) & 1);   // round-to-nearest-even
    return (unsigned short)(r >> 16);
}
__device__ __forceinline__ float bf2f(unsigned short h) {
    union { unsigned u; float f; } v; v.u = ((unsigned)h) << 16; return v.f;
}

__device__ __forceinline__ bf16x8 cvt8(float4 a, float4 b) {
    union { bf16x8 v; unsigned u[4]; } r;
    r.u[0] = (unsigned)f2bf(a.x) | ((unsigned)f2bf(a.y) << 16);
    r.u[1] = (unsigned)f2bf(a.z) | ((unsigned)f2bf(a.w) << 16);
    r.u[2] = (unsigned)f2bf(b.x) | ((unsigned)f2bf(b.y) << 16);
    r.u[3] = (unsigned)f2bf(b.z) | ((unsigned)f2bf(b.w) << 16);
    return r.v;
}

// ---------------- CSR construction ----------------

__global__ void k_hist(const int* __restrict__ row, int E, int* __restrict__ counts) {
    int i = blockIdx.x * 256 + threadIdx.x;
    if (i < E) atomicAdd(&counts[row[i]], 1);
}

__global__ void k_block_sum(const int* __restrict__ counts, int n, int* __restrict__ partials) {
    __shared__ int tmp[256];
    int i = blockIdx.x * 256 + threadIdx.x;
    tmp[threadIdx.x] = (i < n) ? counts[i] : 0;
    __syncthreads();
    for (int o = 128; o > 0; o >>= 1) {
        if (threadIdx.x < o) tmp[threadIdx.x] += tmp[threadIdx.x + o];
        __syncthreads();
    }
    if (threadIdx.x == 0) partials[blockIdx.x] = tmp[0];
}

__global__ void k_scan_partials(int* __restrict__ partials, int nb) {
    __shared__ int tmp[512];
    int t = threadIdx.x;
    int v = (t < nb) ? partials[t] : 0;
    tmp[t] = v;
    __syncthreads();
    for (int o = 1; o < 512; o <<= 1) {
        int add = (t >= o) ? tmp[t - o] : 0;
        __syncthreads();
        tmp[t] += add;
        __syncthreads();
    }
    if (t < nb) partials[t] = tmp[t] - v;   // exclusive
}

// also zeroes counts for reuse as cursor
__global__ void k_scan_counts(int* __restrict__ counts, const int* __restrict__ partials,
                              int* __restrict__ row_ptr, int n) {
    __shared__ int tmp[256];
    int t = threadIdx.x;
    int i = blockIdx.x * 256 + t;
    int v = (i < n) ? counts[i] : 0;
    tmp[t] = v;
    __syncthreads();
    for (int o = 1; o < 256; o <<= 1) {
        int add = (t >= o) ? tmp[t - o] : 0;
        __syncthreads();
        tmp[t] += add;
        __syncthreads();
    }
    int incl = tmp[t];
    int base = partials[blockIdx.x];
    if (i < n) {
        row_ptr[i] = base + incl - v;
        counts[i] = 0;
    }
    if (i == n - 1) row_ptr[n] = base + incl;
}

__global__ void k_scatter(const int* __restrict__ row, const int* __restrict__ col,
                          const float* __restrict__ w, int E,
                          const int* __restrict__ row_ptr, int* __restrict__ cursor,
                          uint2* __restrict__ csr_cw) {
    int i = blockIdx.x * 256 + threadIdx.x;
    if (i < E) {
        int r = row[i];
        int p = row_ptr[r] + atomicAdd(&cursor[r], 1);
        csr_cw[p] = make_uint2((unsigned)col[i], __float_as_uint(w[i]));
    }
}

// ---------------- weight prep: W[K][N] fp32 -> Wt[Nt][Kpad] bf16 (transposed, zero-padded) ----------------

__global__ void k_prep_w(const float* __restrict__ W, unsigned short* __restrict__ Wt,
                         int K, int Norig, int Nt, int Kpad) {
    int idx = blockIdx.x * 256 + threadIdx.x;
    if (idx >= Nt * Kpad) return;
    int n = idx / Kpad, k = idx % Kpad;
    unsigned short v = 0;
    if (k < K && n < Norig) v = f2bf(W[(size_t)k * Norig + n]);
    Wt[idx] = v;
}

// ---------------- Layer-1 GEMM: fp32 A[M][500] @ Wt1^T -> bf16 C[Mpad][128] ----------------
// Rounds 1-4 post-mortem: VGPR software pipelines get COLLAPSED by the register-
// pressure-aware scheduler (r4: VGPR=80, ~1.6KB in flight/CU, 1.07 TB/s Little's-law
// ceiling). Fix: per-WAVE-PRIVATE LDS ring (3 slots x 4KB, 48KB/block) filled with
// __builtin_amdgcn_global_load_lds (no dest registers -> nothing to collapse),
// drained by explicit asm s_waitcnt vmcnt. Waves share nothing -> ZERO barriers.
// Slot = 32 rows x 32 floats of A. gl_lds writes lane-linear (base + lane*16B);
// the SOURCE chunk is pre-swizzled c = (lane&7) ^ ((lane>>3)&7) so that
// LDS[rl][s] holds chunk s ^ (rl&7): fragment ds_read_b128 is then bank-uniform
// (8 accesses/bank = b128 minimum).
// Body j: vmcnt(8) [exactly 8 newer gl_lds outstanding -> slot j landed]
//         -> B frags JIT -> 4x ds_read -> lgkmcnt(0) -> reissue slot (j+3 data,
//         write-after-read safe) -> cvt -> 16 MFMA. In flight/CU ~= 12 waves x
//         4-12KB >> 9-18KB latency-BW product -> BW-bound.

#define GLD1(SLOT, IT)                                                            \
    do {                                                                          \
        __builtin_amdgcn_global_load_lds((gas_t)(gs0 + (IT) * 32),                \
            (las_t)(lb + (SLOT) * 1024 + 0 * 256), 16, 0, 0);                     \
        __builtin_amdgcn_global_load_lds((gas_t)(gs1 + (IT) * 32),                \
            (las_t)(lb + (SLOT) * 1024 + 1 * 256), 16, 0, 0);                     \
        __builtin_amdgcn_global_load_lds((gas_t)(gs2 + (IT) * 32),                \
            (las_t)(lb + (SLOT) * 1024 + 2 * 256), 16, 0, 0);                     \
        __builtin_amdgcn_global_load_lds((gas_t)(gs3 + (IT) * 32),                \
            (las_t)(lb + (SLOT) * 1024 + 3 * 256), 16, 0, 0);                     \
    } while (0)

__global__ __launch_bounds__(256) void k_gemm_l1(const float* __restrict__ A,
                                                 const unsigned short* __restrict__ Wt,
                                                 unsigned short* __restrict__ C, int M) {
    __shared__ __align__(16) float lds[4][3][1024];   // 4 waves x 3 slots x 4KB = 48KB
    const int t = threadIdx.x;
    const int lane = t & 63;
    const int w = t >> 6;
    const int l15 = lane & 15, quad = lane >> 4;
    const int wave = blockIdx.x * 4 + w;
    const int m0 = wave * 32;

    // staging source geometry: instr p covers rows p*8 + (lane>>3); swizzled chunk
    const int srow = lane >> 3;                       // 0..7
    const int sch  = (lane & 7) ^ srow;               // source chunk 0..7 (16B units)
    int sr0 = m0 + srow,      sr1 = m0 + 8 + srow;
    int sr2 = m0 + 16 + srow, sr3 = m0 + 24 + srow;
    sr0 = (sr0 < M) ? sr0 : M - 1;                    // clamp: garbage -> C pad rows only
    sr1 = (sr1 < M) ? sr1 : M - 1;
    sr2 = (sr2 < M) ? sr2 : M - 1;
    sr3 = (sr3 < M) ? sr3 : M - 1;
    const float* gs0 = A + (size_t)sr0 * NFEAT + sch * 4;
    const float* gs1 = A + (size_t)sr1 * NFEAT + sch * 4;
    const float* gs2 = A + (size_t)sr2 * NFEAT + sch * 4;
    const float* gs3 = A + (size_t)sr3 * NFEAT + sch * 4;
    float* lb = &lds[w][0][0];

    f32x4 acc[2][8];
#pragma unroll
    for (int mi = 0; mi < 2; mi++)
#pragma unroll
        for (int ni = 0; ni < 8; ni++)
            acc[mi][ni] = (f32x4){0.f, 0.f, 0.f, 0.f};

    const unsigned short* bp = Wt + (size_t)l15 * 512 + quad * 8;
    const int s0  = (quad * 2) ^ (l15 & 7);           // read-side swizzled slot
    const int ro0 = l15 * 32, ro1 = (16 + l15) * 32;  // row offsets (floats)

    // prologue: fill 3 slots (12 gl_lds in flight)
    GLD1(0, 0);
    GLD1(1, 1);
    GLD1(2, 2);

#pragma unroll
    for (int j = 0; j < 15; ++j) {
        const int slot = j % 3;
        asm volatile("s_waitcnt vmcnt(8)" ::: "memory");   // slot j's 4 loads done
        bf16x8 bfr[8];
#pragma unroll
        for (int ni = 0; ni < 8; ni++)
            bfr[ni] = *(const bf16x8*)(bp + (size_t)(ni * 16) * 512 + j * 32);
        const float* sb = lb + slot * 1024;
        float4 x0 = *(const float4*)(sb + ro0 + s0 * 4);
        float4 x1 = *(const float4*)(sb + ro0 + (s0 ^ 1) * 4);
        float4 y0 = *(const float4*)(sb + ro1 + s0 * 4);
        float4 y1 = *(const float4*)(sb + ro1 + (s0 ^ 1) * 4);
        asm volatile("s_waitcnt lgkmcnt(0)" ::: "memory");  // reads done before overwrite
        if (j + 3 < 15) GLD1(slot, j + 3);
        bf16x8 af0 = cvt8(x0, x1);
        bf16x8 af1 = cvt8(y0, y1);
#pragma unroll
        for (int ni = 0; ni < 8; ni++) {
            acc[0][ni] = __builtin_amdgcn_mfma_f32_16x16x32_bf16(af0, bfr[ni], acc[0][ni], 0, 0, 0);
            acc[1][ni] = __builtin_amdgcn_mfma_f32_16x16x32_bf16(af1, bfr[ni], acc[1][ni], 0, 0, 0);
        }
    }

    // K tail: k = 480..499 (Wt zero-padded to 512; guard only the A reads)
    {
        const int r0 = m0 + l15, r1 = r0 + 16;
        const int rc0 = (r0 < M) ? r0 : M - 1;
        const int rc1 = (r1 < M) ? r1 : M - 1;
        const float* ap0 = A + (size_t)rc0 * NFEAT + quad * 8;
        const float* ap1 = A + (size_t)rc1 * NFEAT + quad * 8;
        bf16x8 bfr[8];
#pragma unroll
        for (int ni = 0; ni < 8; ni++)
            bfr[ni] = *(const bf16x8*)(bp + (size_t)(ni * 16) * 512 + 15 * 32);
        float va[8], vb[8];
#pragma unroll
        for (int jj = 0; jj < 8; jj++) {
            int gk = 480 + quad * 8 + jj;
            va[jj] = (gk < NFEAT) ? ap0[480 + jj] : 0.f;
            vb[jj] = (gk < NFEAT) ? ap1[480 + jj] : 0.f;
        }
        bf16x8 af0 = cvt8(make_float4(va[0], va[1], va[2], va[3]), make_float4(va[4], va[5], va[6], va[7]));
        bf16x8 af1 = cvt8(make_float4(vb[0], vb[1], vb[2], vb[3]), make_float4(vb[4], vb[5], vb[6], vb[7]));
#pragma unroll
        for (int ni = 0; ni < 8; ni++) {
            acc[0][ni] = __builtin_amdgcn_mfma_f32_16x16x32_bf16(af0, bfr[ni], acc[0][ni], 0, 0, 0);
            acc[1][ni] = __builtin_amdgcn_mfma_f32_16x16x32_bf16(af1, bfr[ni], acc[1][ni], 0, 0, 0);
        }
    }

    // epilogue: C/D layout col=lane&15, row=quad*4+reg ; C rows padded, no guards
#pragma unroll
    for (int mi = 0; mi < 2; mi++) {
#pragma unroll
        for (int r = 0; r < 4; r++) {
            int gm = m0 + mi * 16 + quad * 4 + r;
#pragma unroll
            for (int ni = 0; ni < 8; ni++)
                C[(size_t)gm * 128 + ni * 16 + l15] = f2bf(acc[mi][ni][r]);
        }
    }
}

// ---------------- bf16 GEMM (Kpad=128, 4 K-iters): A bf16 [Mpad][128] @ Wt^T ----------------
// All 4 iterations' A fragments issued up-front (8 loads in flight), then
// 4 x (B-frag JIT load + MFMA). No LDS, no barriers, no M guards (padded buffers).

template<int TN, int CN, int CPITCH>
__global__ __launch_bounds__(256) void k_gemm_b(const unsigned short* __restrict__ A,
                                                const unsigned short* __restrict__ Wt,
                                                unsigned short* __restrict__ C) {
    const int t = threadIdx.x;
    const int lane = t & 63;
    const int l15 = lane & 15, quad = lane >> 4;
    const int wave = blockIdx.x * 4 + (t >> 6);
    const int m0 = wave * 32;
    const int r0 = m0 + l15, r1 = r0 + 16;

    const unsigned short* ap0 = A + (size_t)r0 * 128 + quad * 8;
    const unsigned short* ap1 = A + (size_t)r1 * 128 + quad * 8;
    const unsigned short* bp = Wt + (size_t)l15 * 128 + quad * 8;

    f32x4 acc[2][TN];
#pragma unroll
    for (int mi = 0; mi < 2; mi++)
#pragma unroll
        for (int ni = 0; ni < TN; ni++)
            acc[mi][ni] = (f32x4){0.f, 0.f, 0.f, 0.f};

    // all A fragments up-front: 8 x 16B loads in flight
    bf16x8 a00 = *(const bf16x8*)(ap0);       bf16x8 a01 = *(const bf16x8*)(ap1);
    bf16x8 a10 = *(const bf16x8*)(ap0 + 32);  bf16x8 a11 = *(const bf16x8*)(ap1 + 32);
    bf16x8 a20 = *(const bf16x8*)(ap0 + 64);  bf16x8 a21 = *(const bf16x8*)(ap1 + 64);
    bf16x8 a30 = *(const bf16x8*)(ap0 + 96);  bf16x8 a31 = *(const bf16x8*)(ap1 + 96);

#define CMPB(AF0, AF1, IT)                                                                   \
    do {                                                                                     \
        bf16x8 bfr_[TN];                                                                     \
        _Pragma("unroll")                                                                    \
        for (int ni_ = 0; ni_ < TN; ni_++)                                                   \
            bfr_[ni_] = *(const bf16x8*)(bp + (size_t)(ni_ * 16) * 128 + (IT) * 32);         \
        _Pragma("unroll")                                                                    \
        for (int ni_ = 0; ni_ < TN; ni_++) {                                                 \
            acc[0][ni_] = __builtin_amdgcn_mfma_f32_16x16x32_bf16(AF0, bfr_[ni_], acc[0][ni_], 0, 0, 0); \
            acc[1][ni_] = __builtin_amdgcn_mfma_f32_16x16x32_bf16(AF1, bfr_[ni_], acc[1][ni_], 0, 0, 0); \
        }                                                                                    \
    } while (0)

    CMPB(a00, a01, 0);
    CMPB(a10, a11, 1);
    CMPB(a20, a21, 2);
    CMPB(a30, a31, 3);
#undef CMPB

#pragma unroll
    for (int mi = 0; mi < 2; mi++) {
#pragma unroll
        for (int r = 0; r < 4; r++) {
            int gm = m0 + mi * 16 + quad * 4 + r;
#pragma unroll
            for (int ni = 0; ni < TN; ni++) {
                int gn = ni * 16 + l15;
                if (gn < CN) C[(size_t)gm * CPITCH + gn] = f2bf(acc[mi][ni][r]);
            }
        }
    }
}

// ---------------- SpMM (width 128, bf16) + bias + optional ReLU ----------------

__global__ __launch_bounds__(256) void k_spmm128(const unsigned short* __restrict__ S,
                                                 const int* __restrict__ rp,
                                                 const uint2* __restrict__ cw,
                                                 const float* __restrict__ bias,
                                                 unsigned short* __restrict__ out,
                                                 int n, int do_relu) {
    int wid  = threadIdx.x >> 6;
    int lane = threadIdx.x & 63;
    int node = blockIdx.x * 4 + wid;
    if (node >= n) return;
    int s = rp[node], e = rp[node + 1];
    float a0x = 0.f, a0y = 0.f, a1x = 0.f, a1y = 0.f;
    float a2x = 0.f, a2y = 0.f, a3x = 0.f, a3y = 0.f;
    int i = s;
    for (; i + 4 <= e; i += 4) {
        uint2 e0 = cw[i], e1 = cw[i + 1], e2 = cw[i + 2], e3 = cw[i + 3];
        unsigned v0 = ((const unsigned*)(S + (size_t)e0.x * NHID))[lane];
        unsigned v1 = ((const unsigned*)(S + (size_t)e1.x * NHID))[lane];
        unsigned v2 = ((const unsigned*)(S + (size_t)e2.x * NHID))[lane];
        unsigned v3 = ((const unsigned*)(S + (size_t)e3.x * NHID))[lane];
        float w0 = __uint_as_float(e0.y), w1 = __uint_as_float(e1.y);
        float w2 = __uint_as_float(e2.y), w3 = __uint_as_float(e3.y);
        a0x = fmaf(w0, bf2f((unsigned short)v0), a0x); a0y = fmaf(w0, bf2f((unsigned short)(v0 >> 16)), a0y);
        a1x = fmaf(w1, bf2f((unsigned short)v1), a1x); a1y = fmaf(w1, bf2f((unsigned short)(v1 >> 16)), a1y);
        a2x = fmaf(w2, bf2f((unsigned short)v2), a2x); a2y = fmaf(w2, bf2f((unsigned short)(v2 >> 16)), a2y);
        a3x = fmaf(w3, bf2f((unsigned short)v3), a3x); a3y = fmaf(w3, bf2f((unsigned short)(v3 >> 16)), a3y);
    }
    for (; i < e; i++) {
        uint2 e0 = cw[i];
        unsigned v0 = ((const unsigned*)(S + (size_t)e0.x * NHID))[lane];
        float w0 = __uint_as_float(e0.y);
        a0x = fmaf(w0, bf2f((unsigned short)v0), a0x); a0y = fmaf(w0, bf2f((unsigned short)(v0 >> 16)), a0y);
    }
    float ax = (a0x + a1x) + (a2x + a3x) + bias[lane * 2];
    float ay = (a0y + a1y) + (a2y + a3y) + bias[lane * 2 + 1];
    if (do_relu) {
        ax = fmaxf(ax, 0.f);
        ay = fmaxf(ay, 0.f);
    }
    unsigned o = (unsigned)f2bf(ax) | ((unsigned)f2bf(ay) << 16);
    __builtin_nontemporal_store(o, (unsigned*)(out + (size_t)node * NHID) + lane);
}

// ---------------- SpMM (width 40, bf16 pitch 40) + bias + log_softmax -> fp32 out ----------------

__global__ __launch_bounds__(256) void k_spmm40_lsm(const unsigned short* __restrict__ S,
                                                    const int* __restrict__ rp,
                                                    const uint2* __restrict__ cw,
                                                    const float* __restrict__ bias,
                                                    float* __restrict__ out,
                                                    int n) {
    int wid  = threadIdx.x >> 6;
    int lane = threadIdx.x & 63;
    int node = blockIdx.x * 4 + wid;
    if (node >= n) return;
    int s = rp[node], e = rp[node + 1];
    float a0 = 0.f, a1 = 0.f, a2 = 0.f, a3 = 0.f;
    int i = s;
    bool act = lane < NCLASS;
    for (; i + 4 <= e; i += 4) {
        uint2 e0 = cw[i], e1 = cw[i + 1], e2 = cw[i + 2], e3 = cw[i + 3];
        if (act) {
            float v0 = bf2f(S[(size_t)e0.x * NCLASS + lane]);
            float v1 = bf2f(S[(size_t)e1.x * NCLASS + lane]);
            float v2 = bf2f(S[(size_t)e2.x * NCLASS + lane]);
            float v3 = bf2f(S[(size_t)e3.x * NCLASS + lane]);
            a0 = fmaf(__uint_as_float(e0.y), v0, a0);
            a1 = fmaf(__uint_as_float(e1.y), v1, a1);
            a2 = fmaf(__uint_as_float(e2.y), v2, a2);
            a3 = fmaf(__uint_as_float(e3.y), v3, a3);
        }
    }
    for (; i < e; i++) {
        uint2 e0 = cw[i];
        if (act) a0 = fmaf(__uint_as_float(e0.y), bf2f(S[(size_t)e0.x * NCLASS + lane]), a0);
    }
    float acc = (a0 + a1) + (a2 + a3);
    float logit = act ? acc + bias[lane] : -INFINITY;
    float m = logit;
#pragma unroll
    for (int o = 32; o >= 1; o >>= 1) m = fmaxf(m, __shfl_xor(m, o, 64));
    float ex = act ? expf(logit - m) : 0.f;
    float ssum = ex;
#pragma unroll
    for (int o = 32; o >= 1; o >>= 1) ssum += __shfl_xor(ssum, o, 64);
    if (act) {
        float r = logit - m - logf(ssum);
        __builtin_nontemporal_store(r, out + (size_t)node * NCLASS + lane);
    }
}

// ---------------- launch ----------------

extern "C" void kernel_launch(void* const* d_in, const int* in_sizes, int n_in,
                              void* d_out, int out_size, void* d_ws, size_t ws_size,
                              hipStream_t stream) {
    const float* x  = (const float*)d_in[0];
    const int* row  = (const int*)d_in[1];
    const int* col  = (const int*)d_in[2];
    const float* ew = (const float*)d_in[3];
    const float* W1 = (const float*)d_in[4];
    const float* b1 = (const float*)d_in[5];
    const float* W2 = (const float*)d_in[6];
    const float* b2 = (const float*)d_in[7];
    const float* W3 = (const float*)d_in[8];
    const float* b3 = (const float*)d_in[9];
    const float* W4 = (const float*)d_in[10];
    const float* b4 = (const float*)d_in[11];
    float* out = (float*)d_out;

    const int Nn = in_sizes[0] / NFEAT;
    const int E  = in_sizes[1];
    const int NB = (Nn + 255) / 256;
    const int Mpad = (Nn + 127) & ~127;

    char* ws = (char*)d_ws;
    size_t off = 0;
    auto alloc = [&](size_t bytes) {
        size_t o = off;
        off = (off + bytes + 255) & ~(size_t)255;
        return o;
    };
    int*   row_ptr  = (int*)(ws + alloc((size_t)(Nn + 1) * 4));
    int*   counts   = (int*)(ws + alloc((size_t)Nn * 4));       // also reused as cursor
    int*   partials = (int*)(ws + alloc((size_t)NB * 4));
    uint2* csr_cw   = (uint2*)(ws + alloc((size_t)E * 8));
    unsigned short* Sb  = (unsigned short*)(ws + alloc((size_t)Mpad * NHID * 2));
    unsigned short* Hb  = (unsigned short*)(ws + alloc((size_t)Mpad * NHID * 2));
    unsigned short* S4b = (unsigned short*)(ws + alloc((size_t)Mpad * NCLASS * 2));
    unsigned short* Wt1 = (unsigned short*)(ws + alloc((size_t)128 * 512 * 2));
    unsigned short* Wt2 = (unsigned short*)(ws + alloc((size_t)128 * 128 * 2));
    unsigned short* Wt3 = (unsigned short*)(ws + alloc((size_t)128 * 128 * 2));
    unsigned short* Wt4 = (unsigned short*)(ws + alloc((size_t)48 * 128 * 2));

    // ---- weight prep ----
    k_prep_w<<<(128 * 512 + 255) / 256, 256, 0, stream>>>(W1, Wt1, NFEAT, NHID, 128, 512);
    k_prep_w<<<(128 * 128 + 255) / 256, 256, 0, stream>>>(W2, Wt2, NHID, NHID, 128, 128);
    k_prep_w<<<(128 * 128 + 255) / 256, 256, 0, stream>>>(W3, Wt3, NHID, NHID, 128, 128);
    k_prep_w<<<(48 * 128 + 255) / 256, 256, 0, stream>>>(W4, Wt4, NHID, NCLASS, 48, 128);

    // ---- CSR build ----
    (void)hipMemsetAsync(counts, 0, (size_t)Nn * 4, stream);
    k_hist<<<(E + 255) / 256, 256, 0, stream>>>(row, E, counts);
    k_block_sum<<<NB, 256, 0, stream>>>(counts, Nn, partials);
    k_scan_partials<<<1, 512, 0, stream>>>(partials, NB);
    k_scan_counts<<<NB, 256, 0, stream>>>(counts, partials, row_ptr, Nn);
    k_scatter<<<(E + 255) / 256, 256, 0, stream>>>(row, col, ew, E, row_ptr, counts, csr_cw);

    const int gblocks = Mpad / 128;             // 4 waves/block x 32 rows/wave
    const int spmm_blocks = (Nn + 3) / 4;

    // layer 1: x @ W1 -> Sb ; spmm+b1+relu -> Hb
    k_gemm_l1<<<gblocks, 256, 0, stream>>>(x, Wt1, Sb, Nn);
    k_spmm128<<<spmm_blocks, 256, 0, stream>>>(Sb, row_ptr, csr_cw, b1, Hb, Nn, 1);
    // layer 2
    k_gemm_b<8, 128, 128><<<gblocks, 256, 0, stream>>>(Hb, Wt2, Sb);
    k_spmm128<<<spmm_blocks, 256, 0, stream>>>(Sb, row_ptr, csr_cw, b2, Hb, Nn, 1);
    // layer 3
    k_gemm_b<8, 128, 128><<<gblocks, 256, 0, stream>>>(Hb, Wt3, Sb);
    k_spmm128<<<spmm_blocks, 256, 0, stream>>>(Sb, row_ptr, csr_cw, b3, Hb, Nn, 1);
    // layer 4: Hb @ W4 -> S4b[N,40] ; spmm+b4+log_softmax -> out (fp32)
    k_gemm_b<3, 40, 40><<<gblocks, 256, 0, stream>>>(Hb, Wt4, S4b);
    k_spmm40_lsm<<<spmm_blocks, 256, 0, stream>>>(S4b, row_ptr, csr_cw, b4, out, Nn);
}

// Round 6
// 877.285 us; speedup vs baseline: 1.0185x; 1.0088x over previous
//
#include <hip/hip_runtime.h>
#include <cstdint>
#include <cstddef>

#define NFEAT 500
#define NHID  128
#define NCLASS 40

typedef __attribute__((ext_vector_type(8))) short bf16x8;
typedef __attribute__((ext_vector_type(4))) float f32x4;
typedef const __attribute__((address_space(1))) void* gas_t;
typedef __attribute__((address_space(3))) void* las_t;

__device__ __forceinline__ unsigned short f2bf(float f) {
    union { float f; unsigned u; } v; v.f = f;
    unsigned u = v.u;
    unsigned r = u + 0x7FFF + ((u >> 16) & 1);   // round-to-nearest-even
    return (unsigned short)(r >> 16);
}
__device__ __forceinline__ float bf2f(unsigned short h) {
    union { unsigned u; float f; } v; v.u = ((unsigned)h) << 16; return v.f;
}

__device__ __forceinline__ bf16x8 cvt8(float4 a, float4 b) {
    union { bf16x8 v; unsigned u[4]; } r;
    r.u[0] = (unsigned)f2bf(a.x) | ((unsigned)f2bf(a.y) << 16);
    r.u[1] = (unsigned)f2bf(a.z) | ((unsigned)f2bf(a.w) << 16);
    r.u[2] = (unsigned)f2bf(b.x) | ((unsigned)f2bf(b.y) << 16);
    r.u[3] = (unsigned)f2bf(b.z) | ((unsigned)f2bf(b.w) << 16);
    return r.v;
}

// ---------------- CSR construction ----------------

__global__ void k_hist(const int* __restrict__ row, int E, int* __restrict__ counts) {
    int i = blockIdx.x * 256 + threadIdx.x;
    if (i < E) atomicAdd(&counts[row[i]], 1);
}

__global__ void k_block_sum(const int* __restrict__ counts, int n, int* __restrict__ partials) {
    __shared__ int tmp[256];
    int i = blockIdx.x * 256 + threadIdx.x;
    tmp[threadIdx.x] = (i < n) ? counts[i] : 0;
    __syncthreads();
    for (int o = 128; o > 0; o >>= 1) {
        if (threadIdx.x < o) tmp[threadIdx.x] += tmp[threadIdx.x + o];
        __syncthreads();
    }
    if (threadIdx.x == 0) partials[blockIdx.x] = tmp[0];
}

__global__ void k_scan_partials(int* __restrict__ partials, int nb) {
    __shared__ int tmp[512];
    int t = threadIdx.x;
    int v = (t < nb) ? partials[t] : 0;
    tmp[t] = v;
    __syncthreads();
    for (int o = 1; o < 512; o <<= 1) {
        int add = (t >= o) ? tmp[t - o] : 0;
        __syncthreads();
        tmp[t] += add;
        __syncthreads();
    }
    if (t < nb) partials[t] = tmp[t] - v;   // exclusive
}

// also zeroes counts for reuse as cursor
__global__ void k_scan_counts(int* __restrict__ counts, const int* __restrict__ partials,
                              int* __restrict__ row_ptr, int n) {
    __shared__ int tmp[256];
    int t = threadIdx.x;
    int i = blockIdx.x * 256 + t;
    int v = (i < n) ? counts[i] : 0;
    tmp[t] = v;
    __syncthreads();
    for (int o = 1; o < 256; o <<= 1) {
        int add = (t >= o) ? tmp[t - o] : 0;
        __syncthreads();
        tmp[t] += add;
        __syncthreads();
    }
    int incl = tmp[t];
    int base = partials[blockIdx.x];
    if (i < n) {
        row_ptr[i] = base + incl - v;
        counts[i] = 0;
    }
    if (i == n - 1) row_ptr[n] = base + incl;
}

__global__ void k_scatter(const int* __restrict__ row, const int* __restrict__ col,
                          const float* __restrict__ w, int E,
                          const int* __restrict__ row_ptr, int* __restrict__ cursor,
                          uint2* __restrict__ csr_cw) {
    int i = blockIdx.x * 256 + threadIdx.x;
    if (i < E) {
        int r = row[i];
        int p = row_ptr[r] + atomicAdd(&cursor[r], 1);
        csr_cw[p] = make_uint2((unsigned)col[i], __float_as_uint(w[i]));
    }
}

// ---------------- weight prep: W[K][N] fp32 -> Wt[Nt][Kpad] bf16 (transposed, zero-padded) ----------------

__global__ void k_prep_w(const float* __restrict__ W, unsigned short* __restrict__ Wt,
                         int K, int Norig, int Nt, int Kpad) {
    int idx = blockIdx.x * 256 + threadIdx.x;
    if (idx >= Nt * Kpad) return;
    int n = idx / Kpad, k = idx % Kpad;
    unsigned short v = 0;
    if (k < K && n < Norig) v = f2bf(W[(size_t)k * Norig + n]);
    Wt[idx] = v;
}

// ---------------- Layer-1 GEMM: fp32 A[M][500] @ Wt1^T -> bf16 C[Mpad][128] ----------------
// Round-5 post-mortem: the gl_lds ring was correct but B-frag loads issued AFTER the
// ring's gl_lds forced the compiler's B-wait (vmcnt(4)) to DRAIN the whole prefetch
// (vmcnt retires strictly in issue order) -> in-flight ~1.5KB/CU -> 1.0 TB/s.
// Fix: B double-buffered with a ONE-BODY LEAD. Body j issues B(j+1) FIRST, then one
// s_waitcnt vmcnt(N) with N = #ops issued after B(j) (steady: 4 reissue + 8 B = 12).
// Waiting for B(j) (age = 1 body >> L2 latency) passes instantly and everything
// older - including slot j's gl_lds - has retired NATURALLY; slots j+1, j+2 stay in
// flight the whole body. asm ""::"memory" walls pin phase order so the allocator
// cannot sink the B loads (round-4 collapse mechanism). All waits are no-ops in the
// BW-bound steady state; in flight/CU = 8-12 waves x 8-12KB >> Little's-law 9KB.

#define GLD1(SLOT, IT)                                                            \
    do {                                                                          \
        __builtin_amdgcn_global_load_lds((gas_t)(gs0 + (IT) * 32),                \
            (las_t)(lb + (SLOT) * 1024 + 0 * 256), 16, 0, 0);                     \
        __builtin_amdgcn_global_load_lds((gas_t)(gs1 + (IT) * 32),                \
            (las_t)(lb + (SLOT) * 1024 + 1 * 256), 16, 0, 0);                     \
        __builtin_amdgcn_global_load_lds((gas_t)(gs2 + (IT) * 32),                \
            (las_t)(lb + (SLOT) * 1024 + 2 * 256), 16, 0, 0);                     \
        __builtin_amdgcn_global_load_lds((gas_t)(gs3 + (IT) * 32),                \
            (las_t)(lb + (SLOT) * 1024 + 3 * 256), 16, 0, 0);                     \
    } while (0)

#define LOADB(BF, IT)                                                             \
    do {                                                                          \
        _Pragma("unroll")                                                         \
        for (int ni_ = 0; ni_ < 8; ni_++)                                         \
            BF[ni_] = *(const bf16x8*)(bp + (size_t)(ni_ * 16) * 512 + (IT) * 32);\
    } while (0)

#define WALL() asm volatile("" ::: "memory")

// body J: [issue B(J+1)] [vmcnt(NW): B(J)+slot J retired, ring intact]
//         [ds_read slot J] [lgkmcnt(0)] [reissue slot -> J+3] [cvt + 16 MFMA]
#define BODY(J, BCUR, BNXT, NW, DOB, DOG)                                         \
    do {                                                                          \
        if (DOB) { LOADB(BNXT, (J) + 1); }                                        \
        WALL();                                                                   \
        asm volatile("s_waitcnt vmcnt(" NW ")" ::: "memory");                     \
        const float* sb_ = lb + ((J) % 3) * 1024;                                 \
        float4 x0_ = *(const float4*)(sb_ + ro0 + s0 * 4);                        \
        float4 x1_ = *(const float4*)(sb_ + ro0 + (s0 ^ 1) * 4);                  \
        float4 y0_ = *(const float4*)(sb_ + ro1 + s0 * 4);                        \
        float4 y1_ = *(const float4*)(sb_ + ro1 + (s0 ^ 1) * 4);                  \
        asm volatile("s_waitcnt lgkmcnt(0)" ::: "memory");                        \
        if (DOG) { GLD1((J) % 3, (J) + 3); }                                      \
        WALL();                                                                   \
        bf16x8 af0_ = cvt8(x0_, x1_);                                             \
        bf16x8 af1_ = cvt8(y0_, y1_);                                             \
        _Pragma("unroll")                                                         \
        for (int ni_ = 0; ni_ < 8; ni_++) {                                       \
            acc[0][ni_] = __builtin_amdgcn_mfma_f32_16x16x32_bf16(af0_, BCUR[ni_], acc[0][ni_], 0, 0, 0); \
            acc[1][ni_] = __builtin_amdgcn_mfma_f32_16x16x32_bf16(af1_, BCUR[ni_], acc[1][ni_], 0, 0, 0); \
        }                                                                         \
    } while (0)

__global__ __launch_bounds__(256) void k_gemm_l1(const float* __restrict__ A,
                                                 const unsigned short* __restrict__ Wt,
                                                 unsigned short* __restrict__ C, int M) {
    __shared__ __align__(16) float lds[4][3][1024];   // 4 waves x 3 slots x 4KB = 48KB
    const int t = threadIdx.x;
    const int lane = t & 63;
    const int w = t >> 6;
    const int l15 = lane & 15, quad = lane >> 4;
    const int wave = blockIdx.x * 4 + w;
    const int m0 = wave * 32;

    // staging source geometry: instr p covers rows p*8 + (lane>>3); swizzled chunk
    const int srow = lane >> 3;                       // 0..7
    const int sch  = (lane & 7) ^ srow;               // source chunk 0..7 (16B units)
    int sr0 = m0 + srow,      sr1 = m0 + 8 + srow;
    int sr2 = m0 + 16 + srow, sr3 = m0 + 24 + srow;
    sr0 = (sr0 < M) ? sr0 : M - 1;                    // clamp: garbage -> C pad rows only
    sr1 = (sr1 < M) ? sr1 : M - 1;
    sr2 = (sr2 < M) ? sr2 : M - 1;
    sr3 = (sr3 < M) ? sr3 : M - 1;
    const float* gs0 = A + (size_t)sr0 * NFEAT + sch * 4;
    const float* gs1 = A + (size_t)sr1 * NFEAT + sch * 4;
    const float* gs2 = A + (size_t)sr2 * NFEAT + sch * 4;
    const float* gs3 = A + (size_t)sr3 * NFEAT + sch * 4;
    float* lb = &lds[w][0][0];

    f32x4 acc[2][8];
#pragma unroll
    for (int mi = 0; mi < 2; mi++)
#pragma unroll
        for (int ni = 0; ni < 8; ni++)
            acc[mi][ni] = (f32x4){0.f, 0.f, 0.f, 0.f};

    const unsigned short* bp = Wt + (size_t)l15 * 512 + quad * 8;
    const int s0  = (quad * 2) ^ (l15 & 7);           // read-side swizzled slot
    const int ro0 = l15 * 32, ro1 = (16 + l15) * 32;  // row offsets (floats)

    bf16x8 b0[8], b1[8];                              // B double buffer (1-body lead)

    // prologue: GLD(0) < B(0) < GLD(1) < GLD(2)  [issue order matters for vmcnt]
    GLD1(0, 0);
    WALL();
    LOADB(b0, 0);
    WALL();
    GLD1(1, 1);
    GLD1(2, 2);
    WALL();

    // N(j) = #VMEM issued after B(j): j=0: GLD1+GLD2+B(1)=16; 1<=j<=12: reissue(4)+B(8)=12;
    // j=13: B(14) only = 8; j=14: none = 0. Reissue stops at j=12 (12+3=15).
    BODY(0,  b0, b1, "16", 1, 1);
    BODY(1,  b1, b0, "12", 1, 1);
    BODY(2,  b0, b1, "12", 1, 1);
    BODY(3,  b1, b0, "12", 1, 1);
    BODY(4,  b0, b1, "12", 1, 1);
    BODY(5,  b1, b0, "12", 1, 1);
    BODY(6,  b0, b1, "12", 1, 1);
    BODY(7,  b1, b0, "12", 1, 1);
    BODY(8,  b0, b1, "12", 1, 1);
    BODY(9,  b1, b0, "12", 1, 1);
    BODY(10, b0, b1, "12", 1, 1);
    BODY(11, b1, b0, "12", 1, 1);
    BODY(12, b0, b1, "12", 1, 0);
    BODY(13, b1, b0, "8",  1, 0);
    BODY(14, b0, b1, "0",  0, 0);

    // K tail: k = 480..499 (Wt zero-padded to 512; guard only the A reads)
    {
        const int r0 = m0 + l15, r1 = r0 + 16;
        const int rc0 = (r0 < M) ? r0 : M - 1;
        const int rc1 = (r1 < M) ? r1 : M - 1;
        const float* ap0 = A + (size_t)rc0 * NFEAT + quad * 8;
        const float* ap1 = A + (size_t)rc1 * NFEAT + quad * 8;
        bf16x8 bfr[8];
#pragma unroll
        for (int ni = 0; ni < 8; ni++)
            bfr[ni] = *(const bf16x8*)(bp + (size_t)(ni * 16) * 512 + 15 * 32);
        float va[8], vb[8];
#pragma unroll
        for (int jj = 0; jj < 8; jj++) {
            int gk = 480 + quad * 8 + jj;
            va[jj] = (gk < NFEAT) ? ap0[480 + jj] : 0.f;
            vb[jj] = (gk < NFEAT) ? ap1[480 + jj] : 0.f;
        }
        bf16x8 af0 = cvt8(make_float4(va[0], va[1], va[2], va[3]), make_float4(va[4], va[5], va[6], va[7]));
        bf16x8 af1 = cvt8(make_float4(vb[0], vb[1], vb[2], vb[3]), make_float4(vb[4], vb[5], vb[6], vb[7]));
#pragma unroll
        for (int ni = 0; ni < 8; ni++) {
            acc[0][ni] = __builtin_amdgcn_mfma_f32_16x16x32_bf16(af0, bfr[ni], acc[0][ni], 0, 0, 0);
            acc[1][ni] = __builtin_amdgcn_mfma_f32_16x16x32_bf16(af1, bfr[ni], acc[1][ni], 0, 0, 0);
        }
    }

    // epilogue: C/D layout col=lane&15, row=quad*4+reg ; C rows padded, no guards
#pragma unroll
    for (int mi = 0; mi < 2; mi++) {
#pragma unroll
        for (int r = 0; r < 4; r++) {
            int gm = m0 + mi * 16 + quad * 4 + r;
#pragma unroll
            for (int ni = 0; ni < 8; ni++)
                C[(size_t)gm * 128 + ni * 16 + l15] = f2bf(acc[mi][ni][r]);
        }
    }
}

// ---------------- bf16 GEMM (Kpad=128, 4 K-iters): A bf16 [Mpad][128] @ Wt^T ----------------
// All 4 iterations' A fragments issued up-front (8 loads in flight), then
// 4 x (B-frag JIT load + MFMA). No LDS, no barriers, no M guards (padded buffers).

template<int TN, int CN, int CPITCH>
__global__ __launch_bounds__(256) void k_gemm_b(const unsigned short* __restrict__ A,
                                                const unsigned short* __restrict__ Wt,
                                                unsigned short* __restrict__ C) {
    const int t = threadIdx.x;
    const int lane = t & 63;
    const int l15 = lane & 15, quad = lane >> 4;
    const int wave = blockIdx.x * 4 + (t >> 6);
    const int m0 = wave * 32;
    const int r0 = m0 + l15, r1 = r0 + 16;

    const unsigned short* ap0 = A + (size_t)r0 * 128 + quad * 8;
    const unsigned short* ap1 = A + (size_t)r1 * 128 + quad * 8;
    const unsigned short* bp = Wt + (size_t)l15 * 128 + quad * 8;

    f32x4 acc[2][TN];
#pragma unroll
    for (int mi = 0; mi < 2; mi++)
#pragma unroll
        for (int ni = 0; ni < TN; ni++)
            acc[mi][ni] = (f32x4){0.f, 0.f, 0.f, 0.f};

    // all A fragments up-front: 8 x 16B loads in flight
    bf16x8 a00 = *(const bf16x8*)(ap0);       bf16x8 a01 = *(const bf16x8*)(ap1);
    bf16x8 a10 = *(const bf16x8*)(ap0 + 32);  bf16x8 a11 = *(const bf16x8*)(ap1 + 32);
    bf16x8 a20 = *(const bf16x8*)(ap0 + 64);  bf16x8 a21 = *(const bf16x8*)(ap1 + 64);
    bf16x8 a30 = *(const bf16x8*)(ap0 + 96);  bf16x8 a31 = *(const bf16x8*)(ap1 + 96);

#define CMPB(AF0, AF1, IT)                                                                   \
    do {                                                                                     \
        bf16x8 bfr_[TN];                                                                     \
        _Pragma("unroll")                                                                    \
        for (int ni_ = 0; ni_ < TN; ni_++)                                                   \
            bfr_[ni_] = *(const bf16x8*)(bp + (size_t)(ni_ * 16) * 128 + (IT) * 32);         \
        _Pragma("unroll")                                                                    \
        for (int ni_ = 0; ni_ < TN; ni_++) {                                                 \
            acc[0][ni_] = __builtin_amdgcn_mfma_f32_16x16x32_bf16(AF0, bfr_[ni_], acc[0][ni_], 0, 0, 0); \
            acc[1][ni_] = __builtin_amdgcn_mfma_f32_16x16x32_bf16(AF1, bfr_[ni_], acc[1][ni_], 0, 0, 0); \
        }                                                                                    \
    } while (0)

    CMPB(a00, a01, 0);
    CMPB(a10, a11, 1);
    CMPB(a20, a21, 2);
    CMPB(a30, a31, 3);
#undef CMPB

#pragma unroll
    for (int mi = 0; mi < 2; mi++) {
#pragma unroll
        for (int r = 0; r < 4; r++) {
            int gm = m0 + mi * 16 + quad * 4 + r;
#pragma unroll
            for (int ni = 0; ni < TN; ni++) {
                int gn = ni * 16 + l15;
                if (gn < CN) C[(size_t)gm * CPITCH + gn] = f2bf(acc[mi][ni][r]);
            }
        }
    }
}

// ---------------- SpMM (width 128, bf16) + bias + optional ReLU ----------------

__global__ __launch_bounds__(256) void k_spmm128(const unsigned short* __restrict__ S,
                                                 const int* __restrict__ rp,
                                                 const uint2* __restrict__ cw,
                                                 const float* __restrict__ bias,
                                                 unsigned short* __restrict__ out,
                                                 int n, int do_relu) {
    int wid  = threadIdx.x >> 6;
    int lane = threadIdx.x & 63;
    int node = blockIdx.x * 4 + wid;
    if (node >= n) return;
    int s = rp[node], e = rp[node + 1];
    float a0x = 0.f, a0y = 0.f, a1x = 0.f, a1y = 0.f;
    float a2x = 0.f, a2y = 0.f, a3x = 0.f, a3y = 0.f;
    int i = s;
    for (; i + 4 <= e; i += 4) {
        uint2 e0 = cw[i], e1 = cw[i + 1], e2 = cw[i + 2], e3 = cw[i + 3];
        unsigned v0 = ((const unsigned*)(S + (size_t)e0.x * NHID))[lane];
        unsigned v1 = ((const unsigned*)(S + (size_t)e1.x * NHID))[lane];
        unsigned v2 = ((const unsigned*)(S + (size_t)e2.x * NHID))[lane];
        unsigned v3 = ((const unsigned*)(S + (size_t)e3.x * NHID))[lane];
        float w0 = __uint_as_float(e0.y), w1 = __uint_as_float(e1.y);
        float w2 = __uint_as_float(e2.y), w3 = __uint_as_float(e3.y);
        a0x = fmaf(w0, bf2f((unsigned short)v0), a0x); a0y = fmaf(w0, bf2f((unsigned short)(v0 >> 16)), a0y);
        a1x = fmaf(w1, bf2f((unsigned short)v1), a1x); a1y = fmaf(w1, bf2f((unsigned short)(v1 >> 16)), a1y);
        a2x = fmaf(w2, bf2f((unsigned short)v2), a2x); a2y = fmaf(w2, bf2f((unsigned short)(v2 >> 16)), a2y);
        a3x = fmaf(w3, bf2f((unsigned short)v3), a3x); a3y = fmaf(w3, bf2f((unsigned short)(v3 >> 16)), a3y);
    }
    for (; i < e; i++) {
        uint2 e0 = cw[i];
        unsigned v0 = ((const unsigned*)(S + (size_t)e0.x * NHID))[lane];
        float w0 = __uint_as_float(e0.y);
        a0x = fmaf(w0, bf2f((unsigned short)v0), a0x); a0y = fmaf(w0, bf2f((unsigned short)(v0 >> 16)), a0y);
    }
    float ax = (a0x + a1x) + (a2x + a3x) + bias[lane * 2];
    float ay = (a0y + a1y) + (a2y + a3y) + bias[lane * 2 + 1];
    if (do_relu) {
        ax = fmaxf(ax, 0.f);
        ay = fmaxf(ay, 0.f);
    }
    unsigned o = (unsigned)f2bf(ax) | ((unsigned)f2bf(ay) << 16);
    __builtin_nontemporal_store(o, (unsigned*)(out + (size_t)node * NHID) + lane);
}

// ---------------- SpMM (width 40, bf16 pitch 40) + bias + log_softmax -> fp32 out ----------------

__global__ __launch_bounds__(256) void k_spmm40_lsm(const unsigned short* __restrict__ S,
                                                    const int* __restrict__ rp,
                                                    const uint2* __restrict__ cw,
                                                    const float* __restrict__ bias,
                                                    float* __restrict__ out,
                                                    int n) {
    int wid  = threadIdx.x >> 6;
    int lane = threadIdx.x & 63;
    int node = blockIdx.x * 4 + wid;
    if (node >= n) return;
    int s = rp[node], e = rp[node + 1];
    float a0 = 0.f, a1 = 0.f, a2 = 0.f, a3 = 0.f;
    int i = s;
    bool act = lane < NCLASS;
    for (; i + 4 <= e; i += 4) {
        uint2 e0 = cw[i], e1 = cw[i + 1], e2 = cw[i + 2], e3 = cw[i + 3];
        if (act) {
            float v0 = bf2f(S[(size_t)e0.x * NCLASS + lane]);
            float v1 = bf2f(S[(size_t)e1.x * NCLASS + lane]);
            float v2 = bf2f(S[(size_t)e2.x * NCLASS + lane]);
            float v3 = bf2f(S[(size_t)e3.x * NCLASS + lane]);
            a0 = fmaf(__uint_as_float(e0.y), v0, a0);
            a1 = fmaf(__uint_as_float(e1.y), v1, a1);
            a2 = fmaf(__uint_as_float(e2.y), v2, a2);
            a3 = fmaf(__uint_as_float(e3.y), v3, a3);
        }
    }
    for (; i < e; i++) {
        uint2 e0 = cw[i];
        if (act) a0 = fmaf(__uint_as_float(e0.y), bf2f(S[(size_t)e0.x * NCLASS + lane]), a0);
    }
    float acc = (a0 + a1) + (a2 + a3);
    float logit = act ? acc + bias[lane] : -INFINITY;
    float m = logit;
#pragma unroll
    for (int o = 32; o >= 1; o >>= 1) m = fmaxf(m, __shfl_xor(m, o, 64));
    float ex = act ? expf(logit - m) : 0.f;
    float ssum = ex;
#pragma unroll
    for (int o = 32; o >= 1; o >>= 1) ssum += __shfl_xor(ssum, o, 64);
    if (act) {
        float r = logit - m - logf(ssum);
        __builtin_nontemporal_store(r, out + (size_t)node * NCLASS + lane);
    }
}

// ---------------- launch ----------------

extern "C" void kernel_launch(void* const* d_in, const int* in_sizes, int n_in,
                              void* d_out, int out_size, void* d_ws, size_t ws_size,
                              hipStream_t stream) {
    const float* x  = (const float*)d_in[0];
    const int* row  = (const int*)d_in[1];
    const int* col  = (const int*)d_in[2];
    const float* ew = (const float*)d_in[3];
    const float* W1 = (const float*)d_in[4];
    const float* b1 = (const float*)d_in[5];
    const float* W2 = (const float*)d_in[6];
    const float* b2 = (const float*)d_in[7];
    const float* W3 = (const float*)d_in[8];
    const float* b3 = (const float*)d_in[9];
    const float* W4 = (const float*)d_in[10];
    const float* b4 = (const float*)d_in[11];
    float* out = (float*)d_out;

    const int Nn = in_sizes[0] / NFEAT;
    const int E  = in_sizes[1];
    const int NB = (Nn + 255) / 256;
    const int Mpad = (Nn + 127) & ~127;

    char* ws = (char*)d_ws;
    size_t off = 0;
    auto alloc = [&](size_t bytes) {
        size_t o = off;
        off = (off + bytes + 255) & ~(size_t)255;
        return o;
    };
    int*   row_ptr  = (int*)(ws + alloc((size_t)(Nn + 1) * 4));
    int*   counts   = (int*)(ws + alloc((size_t)Nn * 4));       // also reused as cursor
    int*   partials = (int*)(ws + alloc((size_t)NB * 4));
    uint2* csr_cw   = (uint2*)(ws + alloc((size_t)E * 8));
    unsigned short* Sb  = (unsigned short*)(ws + alloc((size_t)Mpad * NHID * 2));
    unsigned short* Hb  = (unsigned short*)(ws + alloc((size_t)Mpad * NHID * 2));
    unsigned short* S4b = (unsigned short*)(ws + alloc((size_t)Mpad * NCLASS * 2));
    unsigned short* Wt1 = (unsigned short*)(ws + alloc((size_t)128 * 512 * 2));
    unsigned short* Wt2 = (unsigned short*)(ws + alloc((size_t)128 * 128 * 2));
    unsigned short* Wt3 = (unsigned short*)(ws + alloc((size_t)128 * 128 * 2));
    unsigned short* Wt4 = (unsigned short*)(ws + alloc((size_t)48 * 128 * 2));

    // ---- weight prep ----
    k_prep_w<<<(128 * 512 + 255) / 256, 256, 0, stream>>>(W1, Wt1, NFEAT, NHID, 128, 512);
    k_prep_w<<<(128 * 128 + 255) / 256, 256, 0, stream>>>(W2, Wt2, NHID, NHID, 128, 128);
    k_prep_w<<<(128 * 128 + 255) / 256, 256, 0, stream>>>(W3, Wt3, NHID, NHID, 128, 128);
    k_prep_w<<<(48 * 128 + 255) / 256, 256, 0, stream>>>(W4, Wt4, NHID, NCLASS, 48, 128);

    // ---- CSR build ----
    (void)hipMemsetAsync(counts, 0, (size_t)Nn * 4, stream);
    k_hist<<<(E + 255) / 256, 256, 0, stream>>>(row, E, counts);
    k_block_sum<<<NB, 256, 0, stream>>>(counts, Nn, partials);
    k_scan_partials<<<1, 512, 0, stream>>>(partials, NB);
    k_scan_counts<<<NB, 256, 0, stream>>>(counts, partials, row_ptr, Nn);
    k_scatter<<<(E + 255) / 256, 256, 0, stream>>>(row, col, ew, E, row_ptr, counts, csr_cw);

    const int gblocks = Mpad / 128;             // 4 waves/block x 32 rows/wave
    const int spmm_blocks = (Nn + 3) / 4;

    // layer 1: x @ W1 -> Sb ; spmm+b1+relu -> Hb
    k_gemm_l1<<<gblocks, 256, 0, stream>>>(x, Wt1, Sb, Nn);
    k_spmm128<<<spmm_blocks, 256, 0, stream>>>(Sb, row_ptr, csr_cw, b1, Hb, Nn, 1);
    // layer 2
    k_gemm_b<8, 128, 128><<<gblocks, 256, 0, stream>>>(Hb, Wt2, Sb);
    k_spmm128<<<spmm_blocks, 256, 0, stream>>>(Sb, row_ptr, csr_cw, b2, Hb, Nn, 1);
    // layer 3
    k_gemm_b<8, 128, 128><<<gblocks, 256, 0, stream>>>(Hb, Wt3, Sb);
    k_spmm128<<<spmm_blocks, 256, 0, stream>>>(Sb, row_ptr, csr_cw, b3, Hb, Nn, 1);
    // layer 4: Hb @ W4 -> S4b[N,40] ; spmm+b4+log_softmax -> out (fp32)
    k_gemm_b<3, 40, 40><<<gblocks, 256, 0, stream>>>(Hb, Wt4, S4b);
    k_spmm40_lsm<<<spmm_blocks, 256, 0, stream>>>(S4b, row_ptr, csr_cw, b4, out, Nn);
}

// Round 7
// 825.305 us; speedup vs baseline: 1.0826x; 1.0630x over previous
//
#include <hip/hip_runtime.h>
#include <cstdint>
#include <cstddef>

#define NFEAT 500
#define NHID  128
#define NCLASS 40

typedef __attribute__((ext_vector_type(8))) short bf16x8;
typedef __attribute__((ext_vector_type(4))) float f32x4;

__device__ __forceinline__ unsigned short f2bf(float f) {
    union { float f; unsigned u; } v; v.f = f;
    unsigned u = v.u;
    unsigned r = u + 0x7FFF + ((u >> 16) & 1);   // round-to-nearest-even
    return (unsigned short)(r >> 16);
}
__device__ __forceinline__ float bf2f(unsigned short h) {
    union { unsigned u; float f; } v; v.u = ((unsigned)h) << 16; return v.f;
}

// ---------------- CSR construction ----------------

__global__ void k_hist(const int* __restrict__ row, int E, int* __restrict__ counts) {
    int i = blockIdx.x * 256 + threadIdx.x;
    if (i < E) atomicAdd(&counts[row[i]], 1);
}

__global__ void k_block_sum(const int* __restrict__ counts, int n, int* __restrict__ partials) {
    __shared__ int tmp[256];
    int i = blockIdx.x * 256 + threadIdx.x;
    tmp[threadIdx.x] = (i < n) ? counts[i] : 0;
    __syncthreads();
    for (int o = 128; o > 0; o >>= 1) {
        if (threadIdx.x < o) tmp[threadIdx.x] += tmp[threadIdx.x + o];
        __syncthreads();
    }
    if (threadIdx.x == 0) partials[blockIdx.x] = tmp[0];
}

__global__ void k_scan_partials(int* __restrict__ partials, int nb) {
    __shared__ int tmp[512];
    int t = threadIdx.x;
    int v = (t < nb) ? partials[t] : 0;
    tmp[t] = v;
    __syncthreads();
    for (int o = 1; o < 512; o <<= 1) {
        int add = (t >= o) ? tmp[t - o] : 0;
        __syncthreads();
        tmp[t] += add;
        __syncthreads();
    }
    if (t < nb) partials[t] = tmp[t] - v;   // exclusive
}

// also zeroes counts for reuse as cursor
__global__ void k_scan_counts(int* __restrict__ counts, const int* __restrict__ partials,
                              int* __restrict__ row_ptr, int n) {
    __shared__ int tmp[256];
    int t = threadIdx.x;
    int i = blockIdx.x * 256 + t;
    int v = (i < n) ? counts[i] : 0;
    tmp[t] = v;
    __syncthreads();
    for (int o = 1; o < 256; o <<= 1) {
        int add = (t >= o) ? tmp[t - o] : 0;
        __syncthreads();
        tmp[t] += add;
        __syncthreads();
    }
    int incl = tmp[t];
    int base = partials[blockIdx.x];
    if (i < n) {
        row_ptr[i] = base + incl - v;
        counts[i] = 0;
    }
    if (i == n - 1) row_ptr[n] = base + incl;
}

__global__ void k_scatter(const int* __restrict__ row, const int* __restrict__ col,
                          const float* __restrict__ w, int E,
                          const int* __restrict__ row_ptr, int* __restrict__ cursor,
                          uint2* __restrict__ csr_cw) {
    int i = blockIdx.x * 256 + threadIdx.x;
    if (i < E) {
        int r = row[i];
        int p = row_ptr[r] + atomicAdd(&cursor[r], 1);
        csr_cw[p] = make_uint2((unsigned)col[i], __float_as_uint(w[i]));
    }
}

// ---------------- weight prep: W[K][N] fp32 -> Wt[Nt][Kpad] bf16 (transposed, zero-padded) ----------------

__global__ void k_prep_w(const float* __restrict__ W, unsigned short* __restrict__ Wt,
                         int K, int Norig, int Nt, int Kpad) {
    int idx = blockIdx.x * 256 + threadIdx.x;
    if (idx >= Nt * Kpad) return;
    int n = idx / Kpad, k = idx % Kpad;
    unsigned short v = 0;
    if (k < K && n < Norig) v = f2bf(W[(size_t)k * Norig + n]);
    Wt[idx] = v;
}

// ---------------- MFMA GEMM (round-0 template, best measured: l1 = 117 us) ----------------
// BM=128, BK=32, 256 threads (4 waves). A: LDS double-buffered with register prefetch,
// ONE barrier per K-iter. B: direct global->fragment loads (Wt is [n][k], exactly MFMA
// B-layout; 128 KB -> L2-resident). BN=128: wave grid 2x2 (64x64/wave, TM=4 TN=4).
// BN=48: 4x1 (32x48/wave, TM=2 TN=3). Buffers padded to Mpad rows; only fp32-A guards M.
// NOTE (rounds 1-6): every "improvement" on this structure (swizzle+deep pipe, no-LDS
// direct, VGPR rotate-3, per-wave gl_lds ring, B-lead vmcnt) measured 137-223 us vs
// this template's 117. The pattern's ~1.2-1.5 TB/s is a latency*outstanding equilibrium
// set by the HW VMEM queue, not by source-level scheduling. Do not re-litigate.

template<bool AFP32, int BN, int CN, int CPITCH>
__global__ __launch_bounds__(256) void k_gemm_mfma(const void* __restrict__ Ain,
                                                   const unsigned short* __restrict__ Wt,
                                                   unsigned short* __restrict__ C,
                                                   int M, int K, int Kpad) {
    constexpr int P  = 40;                     // LDS pitch (ushorts) = 80 B
    constexpr int NW = (BN == 128) ? 2 : 1;
    constexpr int MW = 4 / NW;
    constexpr int TM = 128 / (MW * 16);
    constexpr int TN = BN / (NW * 16);
    __shared__ unsigned short As[2][128][P];   // 20.0 KB total

    const int t = threadIdx.x;
    const int lane = t & 63;
    const int w = t >> 6;
    const int wm = w / NW, wn = w % NW;
    const int mbase = blockIdx.x * 128;
    const int l15 = lane & 15, quad = lane >> 4;

    const float* Af = (const float*)Ain;
    const unsigned short* Ab = (const unsigned short*)Ain;

    f32x4 acc[TM][TN];
#pragma unroll
    for (int mi = 0; mi < TM; mi++)
#pragma unroll
        for (int ni = 0; ni < TN; ni++)
            acc[mi][ni] = (f32x4){0.f, 0.f, 0.f, 0.f};

    // A staging registers (prefetch)
    float4 ra_f[4];   // fp32 path: 16 floats/thread
    uint4  ra_b[2];   // bf16 path: 2x16B/thread

    auto loadA = [&](int k0) {
        if (AFP32) {
#pragma unroll
            for (int p = 0; p < 4; p++) {
                int idx = p * 256 + t;
                int m = idx >> 3, ch = idx & 7;
                int gm = mbase + m, gk = k0 + ch * 4;
                float4 v = make_float4(0.f, 0.f, 0.f, 0.f);
                if (gm < M && gk + 4 <= K) v = *(const float4*)(Af + (size_t)gm * K + gk);
                ra_f[p] = v;
            }
        } else {
#pragma unroll
            for (int p = 0; p < 2; p++) {
                int idx = p * 256 + t;
                int m = idx >> 2, ch = idx & 3;
                ra_b[p] = *(const uint4*)(Ab + (size_t)(mbase + m) * Kpad + k0 + ch * 8);
            }
        }
    };
    auto storeLDS = [&](int buf) {
        if (AFP32) {
#pragma unroll
            for (int p = 0; p < 4; p++) {
                int idx = p * 256 + t;
                int m = idx >> 3, ch = idx & 7;
                float4 v = ra_f[p];
                unsigned long long pk = (unsigned long long)f2bf(v.x)
                                      | ((unsigned long long)f2bf(v.y) << 16)
                                      | ((unsigned long long)f2bf(v.z) << 32)
                                      | ((unsigned long long)f2bf(v.w) << 48);
                *(unsigned long long*)&As[buf][m][ch * 4] = pk;
            }
        } else {
#pragma unroll
            for (int p = 0; p < 2; p++) {
                int idx = p * 256 + t;
                int m = idx >> 2, ch = idx & 3;
                *(uint4*)&As[buf][m][ch * 8] = ra_b[p];
            }
        }
    };

    const int nIter = Kpad >> 5;
    loadA(0);
    storeLDS(0);
    __syncthreads();

    for (int it = 0; it < nIter; it++) {
        const int cur = it & 1;
        const int k0 = it << 5;
        const bool more = (it + 1) < nIter;
        if (more) loadA(k0 + 32);              // global loads in flight over compute

        // B fragments: direct global (L2-hot)
        bf16x8 bfr[TN];
#pragma unroll
        for (int ni = 0; ni < TN; ni++)
            bfr[ni] = *(const bf16x8*)(Wt + (size_t)(wn * (TN * 16) + ni * 16 + l15) * Kpad + k0 + quad * 8);

        bf16x8 afr[TM];
#pragma unroll
        for (int mi = 0; mi < TM; mi++)
            afr[mi] = *(const bf16x8*)&As[cur][wm * (TM * 16) + mi * 16 + l15][quad * 8];

#pragma unroll
        for (int mi = 0; mi < TM; mi++)
#pragma unroll
            for (int ni = 0; ni < TN; ni++)
                acc[mi][ni] = __builtin_amdgcn_mfma_f32_16x16x32_bf16(afr[mi], bfr[ni], acc[mi][ni], 0, 0, 0);

        if (more) {
            storeLDS(cur ^ 1);                 // waits on prefetch, writes other buffer
            __syncthreads();                   // ONE barrier per iter
        }
    }

    // epilogue: C/D layout col=lane&15, row=quad*4+reg ; rows padded, no M guard
#pragma unroll
    for (int mi = 0; mi < TM; mi++) {
#pragma unroll
        for (int r = 0; r < 4; r++) {
            int gm = mbase + wm * (TM * 16) + mi * 16 + quad * 4 + r;
#pragma unroll
            for (int ni = 0; ni < TN; ni++) {
                int gn = wn * (TN * 16) + ni * 16 + l15;
                if (gn < CN) C[(size_t)gm * CPITCH + gn] = f2bf(acc[mi][ni][r]);
            }
        }
    }
}

// ---------------- SpMM (width 128, bf16) + bias + optional ReLU ----------------
// Round-7 change: 8 edges in flight (was 4). Each edge gathers one 256B S-row
// segment (64 lanes x 4B). S = 25.6MB -> per-XCD L2 (4MB) can't hold it -> gathers
// are L3-serviced; if latency-bound, doubling MLP halves exposed latency.

__global__ __launch_bounds__(256) void k_spmm128(const unsigned short* __restrict__ S,
                                                 const int* __restrict__ rp,
                                                 const uint2* __restrict__ cw,
                                                 const float* __restrict__ bias,
                                                 unsigned short* __restrict__ out,
                                                 int n, int do_relu) {
    int wid  = threadIdx.x >> 6;
    int lane = threadIdx.x & 63;
    int node = blockIdx.x * 4 + wid;
    if (node >= n) return;
    int s = rp[node], e = rp[node + 1];
    float a0x = 0.f, a0y = 0.f, a1x = 0.f, a1y = 0.f;
    float a2x = 0.f, a2y = 0.f, a3x = 0.f, a3y = 0.f;
    int i = s;
    for (; i + 8 <= e; i += 8) {
        uint2 e0 = cw[i],     e1 = cw[i + 1], e2 = cw[i + 2], e3 = cw[i + 3];
        uint2 e4 = cw[i + 4], e5 = cw[i + 5], e6 = cw[i + 6], e7 = cw[i + 7];
        unsigned v0 = ((const unsigned*)(S + (size_t)e0.x * NHID))[lane];
        unsigned v1 = ((const unsigned*)(S + (size_t)e1.x * NHID))[lane];
        unsigned v2 = ((const unsigned*)(S + (size_t)e2.x * NHID))[lane];
        unsigned v3 = ((const unsigned*)(S + (size_t)e3.x * NHID))[lane];
        unsigned v4 = ((const unsigned*)(S + (size_t)e4.x * NHID))[lane];
        unsigned v5 = ((const unsigned*)(S + (size_t)e5.x * NHID))[lane];
        unsigned v6 = ((const unsigned*)(S + (size_t)e6.x * NHID))[lane];
        unsigned v7 = ((const unsigned*)(S + (size_t)e7.x * NHID))[lane];
        float w0 = __uint_as_float(e0.y), w1 = __uint_as_float(e1.y);
        float w2 = __uint_as_float(e2.y), w3 = __uint_as_float(e3.y);
        float w4 = __uint_as_float(e4.y), w5 = __uint_as_float(e5.y);
        float w6 = __uint_as_float(e6.y), w7 = __uint_as_float(e7.y);
        a0x = fmaf(w0, bf2f((unsigned short)v0), a0x); a0y = fmaf(w0, bf2f((unsigned short)(v0 >> 16)), a0y);
        a1x = fmaf(w1, bf2f((unsigned short)v1), a1x); a1y = fmaf(w1, bf2f((unsigned short)(v1 >> 16)), a1y);
        a2x = fmaf(w2, bf2f((unsigned short)v2), a2x); a2y = fmaf(w2, bf2f((unsigned short)(v2 >> 16)), a2y);
        a3x = fmaf(w3, bf2f((unsigned short)v3), a3x); a3y = fmaf(w3, bf2f((unsigned short)(v3 >> 16)), a3y);
        a0x = fmaf(w4, bf2f((unsigned short)v4), a0x); a0y = fmaf(w4, bf2f((unsigned short)(v4 >> 16)), a0y);
        a1x = fmaf(w5, bf2f((unsigned short)v5), a1x); a1y = fmaf(w5, bf2f((unsigned short)(v5 >> 16)), a1y);
        a2x = fmaf(w6, bf2f((unsigned short)v6), a2x); a2y = fmaf(w6, bf2f((unsigned short)(v6 >> 16)), a2y);
        a3x = fmaf(w7, bf2f((unsigned short)v7), a3x); a3y = fmaf(w7, bf2f((unsigned short)(v7 >> 16)), a3y);
    }
    for (; i + 4 <= e; i += 4) {
        uint2 e0 = cw[i], e1 = cw[i + 1], e2 = cw[i + 2], e3 = cw[i + 3];
        unsigned v0 = ((const unsigned*)(S + (size_t)e0.x * NHID))[lane];
        unsigned v1 = ((const unsigned*)(S + (size_t)e1.x * NHID))[lane];
        unsigned v2 = ((const unsigned*)(S + (size_t)e2.x * NHID))[lane];
        unsigned v3 = ((const unsigned*)(S + (size_t)e3.x * NHID))[lane];
        float w0 = __uint_as_float(e0.y), w1 = __uint_as_float(e1.y);
        float w2 = __uint_as_float(e2.y), w3 = __uint_as_float(e3.y);
        a0x = fmaf(w0, bf2f((unsigned short)v0), a0x); a0y = fmaf(w0, bf2f((unsigned short)(v0 >> 16)), a0y);
        a1x = fmaf(w1, bf2f((unsigned short)v1), a1x); a1y = fmaf(w1, bf2f((unsigned short)(v1 >> 16)), a1y);
        a2x = fmaf(w2, bf2f((unsigned short)v2), a2x); a2y = fmaf(w2, bf2f((unsigned short)(v2 >> 16)), a2y);
        a3x = fmaf(w3, bf2f((unsigned short)v3), a3x); a3y = fmaf(w3, bf2f((unsigned short)(v3 >> 16)), a3y);
    }
    for (; i < e; i++) {
        uint2 e0 = cw[i];
        unsigned v0 = ((const unsigned*)(S + (size_t)e0.x * NHID))[lane];
        float w0 = __uint_as_float(e0.y);
        a0x = fmaf(w0, bf2f((unsigned short)v0), a0x); a0y = fmaf(w0, bf2f((unsigned short)(v0 >> 16)), a0y);
    }
    float ax = (a0x + a1x) + (a2x + a3x) + bias[lane * 2];
    float ay = (a0y + a1y) + (a2y + a3y) + bias[lane * 2 + 1];
    if (do_relu) {
        ax = fmaxf(ax, 0.f);
        ay = fmaxf(ay, 0.f);
    }
    unsigned o = (unsigned)f2bf(ax) | ((unsigned)f2bf(ay) << 16);
    __builtin_nontemporal_store(o, (unsigned*)(out + (size_t)node * NHID) + lane);
}

// ---------------- SpMM (width 40, bf16 pitch 40) + bias + log_softmax -> fp32 out ----------------
// Same unroll-8 MLP bump as k_spmm128.

__global__ __launch_bounds__(256) void k_spmm40_lsm(const unsigned short* __restrict__ S,
                                                    const int* __restrict__ rp,
                                                    const uint2* __restrict__ cw,
                                                    const float* __restrict__ bias,
                                                    float* __restrict__ out,
                                                    int n) {
    int wid  = threadIdx.x >> 6;
    int lane = threadIdx.x & 63;
    int node = blockIdx.x * 4 + wid;
    if (node >= n) return;
    int s = rp[node], e = rp[node + 1];
    float a0 = 0.f, a1 = 0.f, a2 = 0.f, a3 = 0.f;
    int i = s;
    bool act = lane < NCLASS;
    for (; i + 8 <= e; i += 8) {
        uint2 e0 = cw[i],     e1 = cw[i + 1], e2 = cw[i + 2], e3 = cw[i + 3];
        uint2 e4 = cw[i + 4], e5 = cw[i + 5], e6 = cw[i + 6], e7 = cw[i + 7];
        if (act) {
            float v0 = bf2f(S[(size_t)e0.x * NCLASS + lane]);
            float v1 = bf2f(S[(size_t)e1.x * NCLASS + lane]);
            float v2 = bf2f(S[(size_t)e2.x * NCLASS + lane]);
            float v3 = bf2f(S[(size_t)e3.x * NCLASS + lane]);
            float v4 = bf2f(S[(size_t)e4.x * NCLASS + lane]);
            float v5 = bf2f(S[(size_t)e5.x * NCLASS + lane]);
            float v6 = bf2f(S[(size_t)e6.x * NCLASS + lane]);
            float v7 = bf2f(S[(size_t)e7.x * NCLASS + lane]);
            a0 = fmaf(__uint_as_float(e0.y), v0, a0);
            a1 = fmaf(__uint_as_float(e1.y), v1, a1);
            a2 = fmaf(__uint_as_float(e2.y), v2, a2);
            a3 = fmaf(__uint_as_float(e3.y), v3, a3);
            a0 = fmaf(__uint_as_float(e4.y), v4, a0);
            a1 = fmaf(__uint_as_float(e5.y), v5, a1);
            a2 = fmaf(__uint_as_float(e6.y), v6, a2);
            a3 = fmaf(__uint_as_float(e7.y), v7, a3);
        }
    }
    for (; i + 4 <= e; i += 4) {
        uint2 e0 = cw[i], e1 = cw[i + 1], e2 = cw[i + 2], e3 = cw[i + 3];
        if (act) {
            float v0 = bf2f(S[(size_t)e0.x * NCLASS + lane]);
            float v1 = bf2f(S[(size_t)e1.x * NCLASS + lane]);
            float v2 = bf2f(S[(size_t)e2.x * NCLASS + lane]);
            float v3 = bf2f(S[(size_t)e3.x * NCLASS + lane]);
            a0 = fmaf(__uint_as_float(e0.y), v0, a0);
            a1 = fmaf(__uint_as_float(e1.y), v1, a1);
            a2 = fmaf(__uint_as_float(e2.y), v2, a2);
            a3 = fmaf(__uint_as_float(e3.y), v3, a3);
        }
    }
    for (; i < e; i++) {
        uint2 e0 = cw[i];
        if (act) a0 = fmaf(__uint_as_float(e0.y), bf2f(S[(size_t)e0.x * NCLASS + lane]), a0);
    }
    float acc = (a0 + a1) + (a2 + a3);
    float logit = act ? acc + bias[lane] : -INFINITY;
    float m = logit;
#pragma unroll
    for (int o = 32; o >= 1; o >>= 1) m = fmaxf(m, __shfl_xor(m, o, 64));
    float ex = act ? expf(logit - m) : 0.f;
    float ssum = ex;
#pragma unroll
    for (int o = 32; o >= 1; o >>= 1) ssum += __shfl_xor(ssum, o, 64);
    if (act) {
        float r = logit - m - logf(ssum);
        __builtin_nontemporal_store(r, out + (size_t)node * NCLASS + lane);
    }
}

// ---------------- launch ----------------

extern "C" void kernel_launch(void* const* d_in, const int* in_sizes, int n_in,
                              void* d_out, int out_size, void* d_ws, size_t ws_size,
                              hipStream_t stream) {
    const float* x  = (const float*)d_in[0];
    const int* row  = (const int*)d_in[1];
    const int* col  = (const int*)d_in[2];
    const float* ew = (const float*)d_in[3];
    const float* W1 = (const float*)d_in[4];
    const float* b1 = (const float*)d_in[5];
    const float* W2 = (const float*)d_in[6];
    const float* b2 = (const float*)d_in[7];
    const float* W3 = (const float*)d_in[8];
    const float* b3 = (const float*)d_in[9];
    const float* W4 = (const float*)d_in[10];
    const float* b4 = (const float*)d_in[11];
    float* out = (float*)d_out;

    const int Nn = in_sizes[0] / NFEAT;
    const int E  = in_sizes[1];
    const int NB = (Nn + 255) / 256;
    const int Mpad = (Nn + 127) & ~127;

    char* ws = (char*)d_ws;
    size_t off = 0;
    auto alloc = [&](size_t bytes) {
        size_t o = off;
        off = (off + bytes + 255) & ~(size_t)255;
        return o;
    };
    int*   row_ptr  = (int*)(ws + alloc((size_t)(Nn + 1) * 4));
    int*   counts   = (int*)(ws + alloc((size_t)Nn * 4));       // also reused as cursor
    int*   partials = (int*)(ws + alloc((size_t)NB * 4));
    uint2* csr_cw   = (uint2*)(ws + alloc((size_t)E * 8));
    unsigned short* Sb  = (unsigned short*)(ws + alloc((size_t)Mpad * NHID * 2));
    unsigned short* Hb  = (unsigned short*)(ws + alloc((size_t)Mpad * NHID * 2));
    unsigned short* S4b = (unsigned short*)(ws + alloc((size_t)Mpad * NCLASS * 2));
    unsigned short* Wt1 = (unsigned short*)(ws + alloc((size_t)128 * 512 * 2));
    unsigned short* Wt2 = (unsigned short*)(ws + alloc((size_t)128 * 128 * 2));
    unsigned short* Wt3 = (unsigned short*)(ws + alloc((size_t)128 * 128 * 2));
    unsigned short* Wt4 = (unsigned short*)(ws + alloc((size_t)48 * 128 * 2));

    // ---- weight prep ----
    k_prep_w<<<(128 * 512 + 255) / 256, 256, 0, stream>>>(W1, Wt1, NFEAT, NHID, 128, 512);
    k_prep_w<<<(128 * 128 + 255) / 256, 256, 0, stream>>>(W2, Wt2, NHID, NHID, 128, 128);
    k_prep_w<<<(128 * 128 + 255) / 256, 256, 0, stream>>>(W3, Wt3, NHID, NHID, 128, 128);
    k_prep_w<<<(48 * 128 + 255) / 256, 256, 0, stream>>>(W4, Wt4, NHID, NCLASS, 48, 128);

    // ---- CSR build ----
    (void)hipMemsetAsync(counts, 0, (size_t)Nn * 4, stream);
    k_hist<<<(E + 255) / 256, 256, 0, stream>>>(row, E, counts);
    k_block_sum<<<NB, 256, 0, stream>>>(counts, Nn, partials);
    k_scan_partials<<<1, 512, 0, stream>>>(partials, NB);
    k_scan_counts<<<NB, 256, 0, stream>>>(counts, partials, row_ptr, Nn);
    k_scatter<<<(E + 255) / 256, 256, 0, stream>>>(row, col, ew, E, row_ptr, counts, csr_cw);

    const int gblocks = Mpad / 128;
    const int spmm_blocks = (Nn + 3) / 4;

    // layer 1: x @ W1 -> Sb ; spmm+b1+relu -> Hb
    k_gemm_mfma<true, 128, 128, 128><<<gblocks, 256, 0, stream>>>(x, Wt1, Sb, Nn, NFEAT, 512);
    k_spmm128<<<spmm_blocks, 256, 0, stream>>>(Sb, row_ptr, csr_cw, b1, Hb, Nn, 1);
    // layer 2
    k_gemm_mfma<false, 128, 128, 128><<<gblocks, 256, 0, stream>>>(Hb, Wt2, Sb, Nn, NHID, NHID);
    k_spmm128<<<spmm_blocks, 256, 0, stream>>>(Sb, row_ptr, csr_cw, b2, Hb, Nn, 1);
    // layer 3
    k_gemm_mfma<false, 128, 128, 128><<<gblocks, 256, 0, stream>>>(Hb, Wt3, Sb, Nn, NHID, NHID);
    k_spmm128<<<spmm_blocks, 256, 0, stream>>>(Sb, row_ptr, csr_cw, b3, Hb, Nn, 1);
    // layer 4: Hb @ W4 -> S4b[N,40] ; spmm+b4+log_softmax -> out (fp32)
    k_gemm_mfma<false, 48, 40, 40><<<gblocks, 256, 0, stream>>>(Hb, Wt4, S4b, Nn, NHID, NHID);
    k_spmm40_lsm<<<spmm_blocks, 256, 0, stream>>>(S4b, row_ptr, csr_cw, b4, out, Nn);
}